// Round 12
// baseline (254.038 us; speedup 1.0000x reference)
//
#include <hip/hip_runtime.h>
#include <cstddef>
#include <cstdint>

#define B_ 2
#define S_ 2048
#define DM_ 1024
#define H_ 16
#define DH_ 64
#define NEGV (-1e12f)
// log2(e) / sqrt(DH) folded into Q at projection epilogue
#define QSCALE 0.18033688011112042f
// defer-max threshold in log2 units: P <= 2^12, l <= 2048*4096 -> fp32-safe
#define DEFER_THR 12.0f

typedef __attribute__((ext_vector_type(8))) short bf16x8;
typedef __attribute__((ext_vector_type(4))) float f32x4;

__device__ __forceinline__ unsigned short f2bf(float f) {
    union { float f; uint32_t u; } v; v.f = f;
    uint32_t u = v.u;
    u += 0x7FFF + ((u >> 16) & 1);   // round-to-nearest-even
    return (unsigned short)(u >> 16);
}

// packed f32x2 -> bf16x2 (RNE), single HW instruction (T12 recipe)
__device__ __forceinline__ uint32_t cvt_pk_bf16(float lo, float hi) {
    uint32_t r;
    asm volatile("v_cvt_pk_bf16_f32 %0, %1, %2" : "=v"(r) : "v"(lo), "v"(hi));
    return r;
}

__device__ __forceinline__ void gload_lds16(const void* g, void* l) {
    __builtin_amdgcn_global_load_lds(
        (__attribute__((address_space(1))) void*)g,
        (__attribute__((address_space(3))) void*)l,
        16, 0, 0);
}

// ---------------------------------------------------------------------------
// merged prep: blocks [0,2048): x fp32 -> bf16; blocks [2048,3072): W
// transpose+convert (one launch instead of two)
// ---------------------------------------------------------------------------
__global__ __launch_bounds__(256) void prep_kernel(
    const float* __restrict__ x, ushort* __restrict__ xb,
    const float* __restrict__ W0, const float* __restrict__ W1,
    const float* __restrict__ W2, const float* __restrict__ W3,
    ushort* __restrict__ T0, ushort* __restrict__ T1,
    ushort* __restrict__ T2, ushort* __restrict__ T3)
{
    __shared__ float T[64][65];
    const int tid = threadIdx.x;
    if (blockIdx.x < 2048) {
        const size_t i = ((size_t)blockIdx.x * 256 + tid) * 8;
        const float4 a = *(const float4*)(x + i);
        const float4 b = *(const float4*)(x + i + 4);
        ushort4 u0, u1;
        u0.x = f2bf(a.x); u0.y = f2bf(a.y); u0.z = f2bf(a.z); u0.w = f2bf(a.w);
        u1.x = f2bf(b.x); u1.y = f2bf(b.y); u1.z = f2bf(b.z); u1.w = f2bf(b.w);
        *(ushort4*)(xb + i) = u0;
        *(ushort4*)(xb + i + 4) = u1;
        return;
    }
    const int bid = blockIdx.x - 2048;
    const int sel = bid >> 8;
    const int bt  = bid & 255;
    const float* W = (sel == 0) ? W0 : (sel == 1) ? W1 : (sel == 2) ? W2 : W3;
    ushort* Wt = (sel == 0) ? T0 : (sel == 1) ? T1 : (sel == 2) ? T2 : T3;

    const int n0 = (bt & 15) * 64;
    const int k0 = (bt >> 4) * 64;
    const int tr = tid >> 4, tc = tid & 15;
#pragma unroll
    for (int i = 0; i < 4; ++i) {
        const float4 v = *(const float4*)(W + (size_t)(k0 + tr + i * 16) * 1024 + n0 + tc * 4);
        T[tr + i * 16][tc * 4 + 0] = v.x;
        T[tr + i * 16][tc * 4 + 1] = v.y;
        T[tr + i * 16][tc * 4 + 2] = v.z;
        T[tr + i * 16][tc * 4 + 3] = v.w;
    }
    __syncthreads();
    const int orr = tid >> 2, oc = tid & 3;
#pragma unroll
    for (int j = 0; j < 4; ++j) {
        ushort4 u;
        u.x = f2bf(T[oc * 16 + j * 4 + 0][orr]);
        u.y = f2bf(T[oc * 16 + j * 4 + 1][orr]);
        u.z = f2bf(T[oc * 16 + j * 4 + 2][orr]);
        u.w = f2bf(T[oc * 16 + j * 4 + 3][orr]);
        *(ushort4*)(Wt + (size_t)(n0 + orr) * 1024 + k0 + oc * 16 + j * 4) = u;
    }
}

// ---------------------------------------------------------------------------
// bf16 MFMA GEMM, C = A @ Bt^T (+bias, +epilogue). A[M][1024], Bt[n][1024].
// MODE 1: fused QKV (BM=128, Ntot=3072 in 3 segments; rope epilogues, V transp)
// MODE 0: out-proj  (BM=64, N=1024, fp32 out)
// (unchanged — validated)
// ---------------------------------------------------------------------------
template <int MODE>
__global__ __launch_bounds__(256) void gemm_bf16(
    const ushort* __restrict__ A,
    const ushort* __restrict__ B0, const ushort* __restrict__ B1, const ushort* __restrict__ B2,
    const float* __restrict__ bias0, const float* __restrict__ bias1, const float* __restrict__ bias2,
    const float* __restrict__ pos,
    void* __restrict__ o0, void* __restrict__ o1, void* __restrict__ o2)
{
    constexpr int BM = MODE ? 128 : 64;
    constexpr int BN = 128;
    constexpr int NTN = MODE ? 24 : 8;
    constexpr int A_ISS = BM / 64;
    constexpr int ABYTES = BM * 64;
    constexpr int WM = MODE ? 2 : 1;
    constexpr int TM = BM / WM;
    constexpr int TN = BN / (4 / WM);
    constexpr int MI = TM / 16;
    constexpr int NJ = TN / 16;
    constexpr int NT = DM_ / 32;

    __shared__ char lds[2][(BM + BN) * 64];

    const int tid  = threadIdx.x;
    const int lane = tid & 63;
    const int lc = lane & 15, lg = lane >> 4;
    const int w  = tid >> 6;
    const int wm = MODE ? (w >> 1) : 0;
    const int wn = MODE ? (w & 1) : w;

    const int ntile = blockIdx.x % NTN;
    const int mtile = blockIdx.x / NTN;
    const int m0 = mtile * BM;

    int seg = 0, nseg0 = ntile * 128;
    const ushort* Bt = B0;
    const float* biasp = bias0;
    if constexpr (MODE == 1) {
        seg = ntile >> 3;
        nseg0 = (ntile & 7) * 128;
        Bt = (seg == 0) ? B0 : (seg == 1) ? B1 : B2;
        biasp = (seg == 0) ? bias0 : (seg == 1) ? bias1 : bias2;
    }

    const int sr = tid >> 2;
    const int sc = (tid & 3) * 8;
    const int wub = (tid & 0xC0) * 16;

#define STAGE(BUF, KT)                                                             \
    do {                                                                           \
        const int k0s = (KT) * 32;                                                 \
        char* lb = &lds[BUF][0];                                                   \
        _Pragma("unroll")                                                          \
        for (int ii = 0; ii < A_ISS; ++ii)                                         \
            gload_lds16(A + (size_t)(m0 + ii * 64 + sr) * DM_ + k0s + sc,          \
                        lb + ii * 4096 + wub);                                     \
        _Pragma("unroll")                                                          \
        for (int ii = 0; ii < 2; ++ii)                                             \
            gload_lds16(Bt + (size_t)(nseg0 + ii * 64 + sr) * DM_ + k0s + sc,      \
                        lb + ABYTES + ii * 4096 + wub);                            \
    } while (0)

    f32x4 acc[MI][NJ];
#pragma unroll
    for (int mi = 0; mi < MI; ++mi)
#pragma unroll
        for (int nj = 0; nj < NJ; ++nj) acc[mi][nj] = (f32x4){0.f, 0.f, 0.f, 0.f};

    STAGE(0, 0);

    for (int kt = 0; kt < NT; ++kt) {
        const int cur = kt & 1;
        __syncthreads();
        if (kt + 1 < NT) STAGE(cur ^ 1, kt + 1);
        const char* Ab = &lds[cur][0];
        const char* Bb = Ab + ABYTES;
        bf16x8 af[MI], bfr[NJ];
#pragma unroll
        for (int mi = 0; mi < MI; ++mi)
            af[mi] = *(const bf16x8*)(Ab + (wm * TM + mi * 16 + lc) * 64 + lg * 16);
#pragma unroll
        for (int nj = 0; nj < NJ; ++nj)
            bfr[nj] = *(const bf16x8*)(Bb + (wn * TN + nj * 16 + lc) * 64 + lg * 16);
#pragma unroll
        for (int mi = 0; mi < MI; ++mi)
#pragma unroll
            for (int nj = 0; nj < NJ; ++nj)
                acc[mi][nj] = __builtin_amdgcn_mfma_f32_16x16x32_bf16(af[mi], bfr[nj], acc[mi][nj], 0, 0, 0);
    }
#undef STAGE

    if constexpr (MODE == 0) {
        float* C = (float*)o0;
#pragma unroll
        for (int nj = 0; nj < NJ; ++nj) {
            const int n = nseg0 + wn * TN + nj * 16 + lc;
            const float bn = biasp[n];
#pragma unroll
            for (int mi = 0; mi < MI; ++mi)
#pragma unroll
                for (int r = 0; r < 4; ++r) {
                    const int m = m0 + wm * TM + mi * 16 + lg * 4 + r;
                    C[(size_t)m * DM_ + n] = acc[mi][nj][r] + bn;
                }
        }
    } else {
        if (seg < 2) {
            ushort* C = (seg == 0) ? (ushort*)o0 : (ushort*)o1;
#pragma unroll
            for (int nj = 0; nj < NJ; ++nj) {
                const int n = nseg0 + wn * TN + nj * 16 + lc;
                const float bn = biasp[n];
                const int i2 = (n & 63) & ~1;
                const bool odd = (n & 1) != 0;
#pragma unroll
                for (int mi = 0; mi < MI; ++mi)
#pragma unroll
                    for (int r = 0; r < 4; ++r) {
                        const int m = m0 + wm * TM + mi * 16 + lg * 4 + r;
                        const int s = m & (S_ - 1);
                        const float2 pz = *(const float2*)(pos + (size_t)s * DH_ + i2);
                        const float v = acc[mi][nj][r] + bn;
                        const float pv = __shfl_xor(v, 1);
                        float ov = odd ? (v * pz.y + pv * pz.x) : (v * pz.y - pv * pz.x);
                        if (seg == 0) ov *= QSCALE;
                        C[(size_t)m * (H_ * DH_) + n] = f2bf(ov);
                    }
            }
        } else {
            ushort* C = (ushort*)o2;
#pragma unroll
            for (int nj = 0; nj < NJ; ++nj) {
                const int n = nseg0 + wn * TN + nj * 16 + lc;
                const int hh = n >> 6, dd = n & 63;
                const float bn = biasp[n];
#pragma unroll
                for (int mi = 0; mi < MI; ++mi) {
                    const int mb = m0 + wm * TM + mi * 16 + lg * 4;
                    const int bb = mb >> 11, ss = mb & (S_ - 1);
                    ushort4 u;
                    u.x = f2bf(acc[mi][nj][0] + bn);
                    u.y = f2bf(acc[mi][nj][1] + bn);
                    u.z = f2bf(acc[mi][nj][2] + bn);
                    u.w = f2bf(acc[mi][nj][3] + bn);
                    *(ushort4*)(C + ((size_t)(bb * H_ + hh) * DH_ + dd) * S_ + ss) = u;
                }
            }
        }
    }
}

// ---------------------------------------------------------------------------
// bf16 MFMA flash attention — round 12: round-7 kernel (84.3 µs measured)
// with ONE change (m169 precedent): V is NOT staged in LDS. V^T fragments
// are 16B-contiguous in global Vt[d][s]; the 8KB tile is re-read by all 8
// waves -> L1-served, KV panels shared by 16 blocks -> L2-resident. Removes
// 64 ds_read_b128 + 32 ds-write wave-ops per block-tile from the bound
// DS pipe. V loads issued at SOFTMAX_PV entry so softmax hides latency.
// Same double-buffer 2-barrier pipeline (QK one tile ahead) as r7.
// ---------------------------------------------------------------------------
__global__ __launch_bounds__(512) void attn_mfma_kernel(
    const short* __restrict__ Qb, const short* __restrict__ Kb,
    const short* __restrict__ Vt, const int* __restrict__ vmask,
    ushort* __restrict__ O)
{
    __shared__ short Ks[2][64 * 64];
    __shared__ float bias_s[2][64];

    const int tid  = threadIdx.x;
    const int lane = tid & 63;
    const int w    = tid >> 6;        // 0..7
    const int c    = lane & 15;
    const int g    = lane >> 4;

    const int bid = blockIdx.x;       // b*256 + h*16 + qc  (qc low: L2 reuse)
    const int qc = bid & 15;
    const int h  = (bid >> 4) & 15;
    const int b  = bid >> 8;
    const int s0 = qc * 128;

    // Q fragments (B-operand): lane holds Q[q = lane&15][k = g*8 + j]
    bf16x8 qf[2];
    {
        const size_t qbase = ((size_t)(b * S_ + s0 + w * 16 + c)) * DM_ + h * DH_ + g * 8;
        qf[0] = *(const bf16x8*)(Qb + qbase);
        qf[1] = *(const bf16x8*)(Qb + qbase + 32);
    }

    // K staging: 512 threads, one 16B chunk per thread
    const int kr0 = tid >> 3, kc0 = tid & 7;
    const size_t kpan = ((size_t)b * S_) * DM_ + h * DH_;
    const size_t vpan = ((size_t)(b * H_ + h) * DH_) * S_;

    uint4 kv0;
    int mskv = 1;
    constexpr int NT = S_ / 64;

#define LOAD_TILE(KT)                                                            \
    do {                                                                         \
        kv0 = *(const uint4*)(Kb + kpan + (size_t)((KT) * 64 + kr0) * DM_ + kc0 * 8); \
        if (tid < 64) mskv = vmask[b * S_ + (KT) * 64 + tid];                    \
    } while (0)

#define STORE_TILE(BUF)                                                          \
    do {                                                                         \
        *(uint4*)&Ks[BUF][kr0 * 64 + ((kc0 ^ (kr0 & 7)) * 8)] = kv0;             \
        if (tid < 64) bias_s[BUF][tid] = mskv ? 0.f : NEGV;                      \
    } while (0)

// QK^T (swapped): ACC[km] = S^T[key][q=c], init with mask bias
#define QK_TILE(ACC, BUF)                                                        \
    do {                                                                         \
        _Pragma("unroll")                                                        \
        for (int km = 0; km < 4; ++km)                                           \
            ACC[km] = *(const f32x4*)&bias_s[BUF][km * 16 + g * 4];              \
        _Pragma("unroll")                                                        \
        for (int km = 0; km < 4; ++km) {                                         \
            const int krow = km * 16 + c;                                        \
            const int swz = krow & 7;                                            \
            _Pragma("unroll")                                                    \
            for (int t2 = 0; t2 < 2; ++t2) {                                     \
                const bf16x8 kf = *(const bf16x8*)&Ks[BUF][krow * 64 +           \
                                        (((t2 * 4 + g) ^ swz) * 8)];             \
                ACC[km] = __builtin_amdgcn_mfma_f32_16x16x32_bf16(               \
                              kf, qf[t2], ACC[km], 0, 0, 0);                     \
            }                                                                    \
        }                                                                        \
    } while (0)

// softmax (defer-max) + P->bf16 + bpermute redistribution + PV with V
// fragments loaded DIRECTLY from global (issued first for latency hiding)
#define SOFTMAX_PV(ACC, KT)                                                      \
    do {                                                                         \
        bf16x8 vfr0[4], vfr1[4];                                                 \
        _Pragma("unroll")                                                        \
        for (int dg = 0; dg < 4; ++dg) {                                         \
            const size_t vrow = vpan + (size_t)(dg * 16 + c) * S_ + (KT) * 64;   \
            vfr0[dg] = *(const bf16x8*)(Vt + vrow + g * 8);                      \
            vfr1[dg] = *(const bf16x8*)(Vt + vrow + 32 + g * 8);                 \
        }                                                                        \
        float pm = -1e30f;                                                       \
        _Pragma("unroll")                                                        \
        for (int km = 0; km < 4; ++km)                                           \
            _Pragma("unroll")                                                    \
            for (int r = 0; r < 4; ++r) pm = fmaxf(pm, ACC[km][r]);              \
        pm = fmaxf(pm, __shfl_xor(pm, 16));                                      \
        pm = fmaxf(pm, __shfl_xor(pm, 32));                                      \
        if (!__all(pm <= m_run + DEFER_THR)) {                                   \
            const float m_new = fmaxf(m_run, pm);                                \
            const float sc = exp2f(m_run - m_new);                               \
            _Pragma("unroll")                                                    \
            for (int r = 0; r < 4; ++r) {                                        \
                const float scr = __shfl(sc, (lane & 48) | (g * 4 + r));         \
                _Pragma("unroll")                                                \
                for (int dg = 0; dg < 4; ++dg) acc_o[dg][r] *= scr;              \
            }                                                                    \
            l_run *= sc;                                                         \
            m_run = m_new;                                                       \
        }                                                                        \
        float p[16];                                                             \
        float tsum = 0.f;                                                        \
        _Pragma("unroll")                                                        \
        for (int km = 0; km < 4; ++km)                                           \
            _Pragma("unroll")                                                    \
            for (int r = 0; r < 4; ++r) {                                        \
                const float e = exp2f(ACC[km][r] - m_run);                       \
                p[km * 4 + r] = e;                                               \
                tsum += e;                                                       \
            }                                                                    \
        tsum += __shfl_xor(tsum, 16);                                            \
        tsum += __shfl_xor(tsum, 32);                                            \
        l_run += tsum;                                                           \
        uint32_t pk[4][2];                                                       \
        _Pragma("unroll")                                                        \
        for (int km = 0; km < 4; ++km) {                                         \
            pk[km][0] = cvt_pk_bf16(p[km * 4 + 0], p[km * 4 + 1]);               \
            pk[km][1] = cvt_pk_bf16(p[km * 4 + 2], p[km * 4 + 3]);               \
        }                                                                        \
        _Pragma("unroll")                                                        \
        for (int t2 = 0; t2 < 2; ++t2) {                                         \
            uint32_t fw[4];                                                      \
            _Pragma("unroll")                                                    \
            for (int w2 = 0; w2 < 4; ++w2) {                                     \
                const int src = (w2 < 2) ? srcA : srcB;                          \
                const uint32_t vlo = (uint32_t)__builtin_amdgcn_ds_bpermute(     \
                    src, (int)pk[2 * t2][w2 & 1]);                               \
                const uint32_t vhi = (uint32_t)__builtin_amdgcn_ds_bpermute(     \
                    src, (int)pk[2 * t2 + 1][w2 & 1]);                           \
                fw[w2] = hiSel ? vhi : vlo;                                      \
            }                                                                    \
            union { uint32_t u[4]; bf16x8 v; } pf;                               \
            pf.u[0] = fw[0]; pf.u[1] = fw[1]; pf.u[2] = fw[2]; pf.u[3] = fw[3];  \
            _Pragma("unroll")                                                    \
            for (int dg = 0; dg < 4; ++dg) {                                     \
                const bf16x8 vf = (t2 == 0) ? vfr0[dg] : vfr1[dg];               \
                acc_o[dg] = __builtin_amdgcn_mfma_f32_16x16x32_bf16(             \
                                pf.v, vf, acc_o[dg], 0, 0, 0);                   \
            }                                                                    \
        }                                                                        \
    } while (0)

    float m_run = -1e30f, l_run = 0.f;
    f32x4 acc_o[4];
#pragma unroll
    for (int dg = 0; dg < 4; ++dg) acc_o[dg] = (f32x4){0.f, 0.f, 0.f, 0.f};

    const int srcA = ((((g & 1) * 2) << 4) + c) * 4;
    const int srcB = ((((g & 1) * 2 + 1) << 4) + c) * 4;
    const bool hiSel = (lane >= 32);

    // ---- prologue: tile 0 into buf0, QK(0)
    LOAD_TILE(0);
    STORE_TILE(0);
    __syncthreads();
    LOAD_TILE(1);
    f32x4 acc_t[4];
    QK_TILE(acc_t, 0);

    // ---- main loop: iteration kt issues QK(kt+1), finishes tile kt
    for (int kt = 0; kt < NT - 1; ++kt) {
        const int cur = kt & 1, nxt = cur ^ 1;
        STORE_TILE(nxt);                       // regs hold tile kt+1
        __syncthreads();
        if (kt + 2 < NT) LOAD_TILE(kt + 2);    // prefetch tile kt+2 into regs
        f32x4 acc_n[4];
        QK_TILE(acc_n, nxt);                   // MFMA pipe: scores(kt+1)
        SOFTMAX_PV(acc_t, kt);                 // VALU overlaps MFMA above
#pragma unroll
        for (int km = 0; km < 4; ++km) acc_t[km] = acc_n[km];
        __syncthreads();                       // protect buf[cur] before overwrite
    }
    // ---- epilogue: finish last tile
    SOFTMAX_PV(acc_t, NT - 1);

#undef LOAD_TILE
#undef STORE_TILE
#undef QK_TILE
#undef SOFTMAX_PV

    // ---- normalize and write O (bf16)
    const float linv = 1.0f / l_run;
#pragma unroll
    for (int r = 0; r < 4; ++r) {
        const float lr = __shfl(linv, (lane & 48) | (g * 4 + r));
        const int row = s0 + w * 16 + g * 4 + r;
        const size_t ob = ((size_t)(b * S_ + row)) * DM_ + h * DH_;
#pragma unroll
        for (int dg = 0; dg < 4; ++dg)
            O[ob + dg * 16 + c] = f2bf(acc_o[dg][r] * lr);
    }
}

// ---------------------------------------------------------------------------
extern "C" void kernel_launch(void* const* d_in, const int* in_sizes, int n_in,
                              void* d_out, int out_size, void* d_ws, size_t ws_size,
                              hipStream_t stream)
{
    const float* x     = (const float*)d_in[0];
    const int*   vmask = (const int*)d_in[1];
    const float* pos   = (const float*)d_in[2];
    const float* Wq    = (const float*)d_in[3];
    const float* bq    = (const float*)d_in[4];
    const float* Wk    = (const float*)d_in[5];
    const float* bk    = (const float*)d_in[6];
    const float* Wv    = (const float*)d_in[7];
    const float* bv    = (const float*)d_in[8];
    const float* Wo    = (const float*)d_in[9];
    const float* bo    = (const float*)d_in[10];
    float* out = (float*)d_out;

    const size_t MN = (size_t)(B_ * S_) * (H_ * DH_);   // 4M

    ushort* xb  = (ushort*)d_ws;          // 8 MB
    ushort* Wtq = xb + MN;                // 2 MB each
    ushort* Wtk = Wtq + 1024 * 1024;
    ushort* Wtv = Wtk + 1024 * 1024;
    ushort* Wto = Wtv + 1024 * 1024;
    ushort* Qb  = Wto + 1024 * 1024;      // 8 MB each
    ushort* Kb  = Qb + MN;
    ushort* Vt  = Kb + MN;
    ushort* Ob  = Vt + MN;

    // merged prep: x conversion (2048 blocks) + 4 weight transposes (1024)
    prep_kernel<<<3072, 256, 0, stream>>>(x, xb, Wq, Wk, Wv, Wo,
                                          Wtq, Wtk, Wtv, Wto);

    // fused QKV: grid = (4096/128) m-tiles x 24 n-tiles = 768 blocks (3/CU)
    gemm_bf16<1><<<768, 256, 0, stream>>>(xb, Wtq, Wtk, Wtv, bq, bk, bv, pos,
                                          (void*)Qb, (void*)Kb, (void*)Vt);

    // attention: 512 blocks x 512 threads (128 q-rows/block, 2 blocks/CU)
    attn_mfma_kernel<<<B_ * H_ * (S_ / 128), 512, 0, stream>>>(
        (const short*)Qb, (const short*)Kb, (const short*)Vt, vmask, Ob);

    // out-proj: grid = (4096/64) x 8 = 512 blocks (2/CU)
    gemm_bf16<0><<<512, 256, 0, stream>>>(Ob, Wto, nullptr, nullptr, bo, nullptr, nullptr,
                                          nullptr, (void*)out, nullptr, nullptr);
}

// Round 13
// 176.145 us; speedup vs baseline: 1.4422x; 1.4422x over previous
//
#include <hip/hip_runtime.h>
#include <cstddef>
#include <cstdint>

#define B_ 2
#define S_ 2048
#define DM_ 1024
#define H_ 16
#define DH_ 64
#define NEGV (-1e12f)
// log2(e) / sqrt(DH) folded into Q at projection epilogue
#define QSCALE 0.18033688011112042f
// defer-max threshold in log2 units: P <= 2^12 -> fp32-safe
#define DEFER_THR 12.0f

typedef __attribute__((ext_vector_type(8))) short bf16x8;
typedef __attribute__((ext_vector_type(4))) float f32x4;

__device__ __forceinline__ unsigned short f2bf(float f) {
    union { float f; uint32_t u; } v; v.f = f;
    uint32_t u = v.u;
    u += 0x7FFF + ((u >> 16) & 1);   // round-to-nearest-even
    return (unsigned short)(u >> 16);
}

// packed f32x2 -> bf16x2 (RNE), single HW instruction (T12 recipe)
__device__ __forceinline__ uint32_t cvt_pk_bf16(float lo, float hi) {
    uint32_t r;
    asm volatile("v_cvt_pk_bf16_f32 %0, %1, %2" : "=v"(r) : "v"(lo), "v"(hi));
    return r;
}

__device__ __forceinline__ void gload_lds16(const void* g, void* l) {
    __builtin_amdgcn_global_load_lds(
        (__attribute__((address_space(1))) void*)g,
        (__attribute__((address_space(3))) void*)l,
        16, 0, 0);
}

// ---------------------------------------------------------------------------
// merged prep: blocks [0,2048): x fp32 -> bf16; blocks [2048,3072): W
// transpose+convert (validated r12)
// ---------------------------------------------------------------------------
__global__ __launch_bounds__(256) void prep_kernel(
    const float* __restrict__ x, ushort* __restrict__ xb,
    const float* __restrict__ W0, const float* __restrict__ W1,
    const float* __restrict__ W2, const float* __restrict__ W3,
    ushort* __restrict__ T0, ushort* __restrict__ T1,
    ushort* __restrict__ T2, ushort* __restrict__ T3)
{
    __shared__ float T[64][65];
    const int tid = threadIdx.x;
    if (blockIdx.x < 2048) {
        const size_t i = ((size_t)blockIdx.x * 256 + tid) * 8;
        const float4 a = *(const float4*)(x + i);
        const float4 b = *(const float4*)(x + i + 4);
        ushort4 u0, u1;
        u0.x = f2bf(a.x); u0.y = f2bf(a.y); u0.z = f2bf(a.z); u0.w = f2bf(a.w);
        u1.x = f2bf(b.x); u1.y = f2bf(b.y); u1.z = f2bf(b.z); u1.w = f2bf(b.w);
        *(ushort4*)(xb + i) = u0;
        *(ushort4*)(xb + i + 4) = u1;
        return;
    }
    const int bid = blockIdx.x - 2048;
    const int sel = bid >> 8;
    const int bt  = bid & 255;
    const float* W = (sel == 0) ? W0 : (sel == 1) ? W1 : (sel == 2) ? W2 : W3;
    ushort* Wt = (sel == 0) ? T0 : (sel == 1) ? T1 : (sel == 2) ? T2 : T3;

    const int n0 = (bt & 15) * 64;
    const int k0 = (bt >> 4) * 64;
    const int tr = tid >> 4, tc = tid & 15;
#pragma unroll
    for (int i = 0; i < 4; ++i) {
        const float4 v = *(const float4*)(W + (size_t)(k0 + tr + i * 16) * 1024 + n0 + tc * 4);
        T[tr + i * 16][tc * 4 + 0] = v.x;
        T[tr + i * 16][tc * 4 + 1] = v.y;
        T[tr + i * 16][tc * 4 + 2] = v.z;
        T[tr + i * 16][tc * 4 + 3] = v.w;
    }
    __syncthreads();
    const int orr = tid >> 2, oc = tid & 3;
#pragma unroll
    for (int j = 0; j < 4; ++j) {
        ushort4 u;
        u.x = f2bf(T[oc * 16 + j * 4 + 0][orr]);
        u.y = f2bf(T[oc * 16 + j * 4 + 1][orr]);
        u.z = f2bf(T[oc * 16 + j * 4 + 2][orr]);
        u.w = f2bf(T[oc * 16 + j * 4 + 3][orr]);
        *(ushort4*)(Wt + (size_t)(n0 + orr) * 1024 + k0 + oc * 16 + j * 4) = u;
    }
}

// ---------------------------------------------------------------------------
// bf16 MFMA GEMM, C = A @ Bt^T (+bias, +epilogue). (unchanged — validated)
// ---------------------------------------------------------------------------
template <int MODE>
__global__ __launch_bounds__(256) void gemm_bf16(
    const ushort* __restrict__ A,
    const ushort* __restrict__ B0, const ushort* __restrict__ B1, const ushort* __restrict__ B2,
    const float* __restrict__ bias0, const float* __restrict__ bias1, const float* __restrict__ bias2,
    const float* __restrict__ pos,
    void* __restrict__ o0, void* __restrict__ o1, void* __restrict__ o2)
{
    constexpr int BM = MODE ? 128 : 64;
    constexpr int BN = 128;
    constexpr int NTN = MODE ? 24 : 8;
    constexpr int A_ISS = BM / 64;
    constexpr int ABYTES = BM * 64;
    constexpr int WM = MODE ? 2 : 1;
    constexpr int TM = BM / WM;
    constexpr int TN = BN / (4 / WM);
    constexpr int MI = TM / 16;
    constexpr int NJ = TN / 16;
    constexpr int NT = DM_ / 32;

    __shared__ char lds[2][(BM + BN) * 64];

    const int tid  = threadIdx.x;
    const int lane = tid & 63;
    const int lc = lane & 15, lg = lane >> 4;
    const int w  = tid >> 6;
    const int wm = MODE ? (w >> 1) : 0;
    const int wn = MODE ? (w & 1) : w;

    const int ntile = blockIdx.x % NTN;
    const int mtile = blockIdx.x / NTN;
    const int m0 = mtile * BM;

    int seg = 0, nseg0 = ntile * 128;
    const ushort* Bt = B0;
    const float* biasp = bias0;
    if constexpr (MODE == 1) {
        seg = ntile >> 3;
        nseg0 = (ntile & 7) * 128;
        Bt = (seg == 0) ? B0 : (seg == 1) ? B1 : B2;
        biasp = (seg == 0) ? bias0 : (seg == 1) ? bias1 : bias2;
    }

    const int sr = tid >> 2;
    const int sc = (tid & 3) * 8;
    const int wub = (tid & 0xC0) * 16;

#define STAGE(BUF, KT)                                                             \
    do {                                                                           \
        const int k0s = (KT) * 32;                                                 \
        char* lb = &lds[BUF][0];                                                   \
        _Pragma("unroll")                                                          \
        for (int ii = 0; ii < A_ISS; ++ii)                                         \
            gload_lds16(A + (size_t)(m0 + ii * 64 + sr) * DM_ + k0s + sc,          \
                        lb + ii * 4096 + wub);                                     \
        _Pragma("unroll")                                                          \
        for (int ii = 0; ii < 2; ++ii)                                             \
            gload_lds16(Bt + (size_t)(nseg0 + ii * 64 + sr) * DM_ + k0s + sc,      \
                        lb + ABYTES + ii * 4096 + wub);                            \
    } while (0)

    f32x4 acc[MI][NJ];
#pragma unroll
    for (int mi = 0; mi < MI; ++mi)
#pragma unroll
        for (int nj = 0; nj < NJ; ++nj) acc[mi][nj] = (f32x4){0.f, 0.f, 0.f, 0.f};

    STAGE(0, 0);

    for (int kt = 0; kt < NT; ++kt) {
        const int cur = kt & 1;
        __syncthreads();
        if (kt + 1 < NT) STAGE(cur ^ 1, kt + 1);
        const char* Ab = &lds[cur][0];
        const char* Bb = Ab + ABYTES;
        bf16x8 af[MI], bfr[NJ];
#pragma unroll
        for (int mi = 0; mi < MI; ++mi)
            af[mi] = *(const bf16x8*)(Ab + (wm * TM + mi * 16 + lc) * 64 + lg * 16);
#pragma unroll
        for (int nj = 0; nj < NJ; ++nj)
            bfr[nj] = *(const bf16x8*)(Bb + (wn * TN + nj * 16 + lc) * 64 + lg * 16);
#pragma unroll
        for (int mi = 0; mi < MI; ++mi)
#pragma unroll
            for (int nj = 0; nj < NJ; ++nj)
                acc[mi][nj] = __builtin_amdgcn_mfma_f32_16x16x32_bf16(af[mi], bfr[nj], acc[mi][nj], 0, 0, 0);
    }
#undef STAGE

    if constexpr (MODE == 0) {
        float* C = (float*)o0;
#pragma unroll
        for (int nj = 0; nj < NJ; ++nj) {
            const int n = nseg0 + wn * TN + nj * 16 + lc;
            const float bn = biasp[n];
#pragma unroll
            for (int mi = 0; mi < MI; ++mi)
#pragma unroll
                for (int r = 0; r < 4; ++r) {
                    const int m = m0 + wm * TM + mi * 16 + lg * 4 + r;
                    C[(size_t)m * DM_ + n] = acc[mi][nj][r] + bn;
                }
        }
    } else {
        if (seg < 2) {
            ushort* C = (seg == 0) ? (ushort*)o0 : (ushort*)o1;
#pragma unroll
            for (int nj = 0; nj < NJ; ++nj) {
                const int n = nseg0 + wn * TN + nj * 16 + lc;
                const float bn = biasp[n];
                const int i2 = (n & 63) & ~1;
                const bool odd = (n & 1) != 0;
#pragma unroll
                for (int mi = 0; mi < MI; ++mi)
#pragma unroll
                    for (int r = 0; r < 4; ++r) {
                        const int m = m0 + wm * TM + mi * 16 + lg * 4 + r;
                        const int s = m & (S_ - 1);
                        const float2 pz = *(const float2*)(pos + (size_t)s * DH_ + i2);
                        const float v = acc[mi][nj][r] + bn;
                        const float pv = __shfl_xor(v, 1);
                        float ov = odd ? (v * pz.y + pv * pz.x) : (v * pz.y - pv * pz.x);
                        if (seg == 0) ov *= QSCALE;
                        C[(size_t)m * (H_ * DH_) + n] = f2bf(ov);
                    }
            }
        } else {
            ushort* C = (ushort*)o2;
#pragma unroll
            for (int nj = 0; nj < NJ; ++nj) {
                const int n = nseg0 + wn * TN + nj * 16 + lc;
                const int hh = n >> 6, dd = n & 63;
                const float bn = biasp[n];
#pragma unroll
                for (int mi = 0; mi < MI; ++mi) {
                    const int mb = m0 + wm * TM + mi * 16 + lg * 4;
                    const int bb = mb >> 11, ss = mb & (S_ - 1);
                    ushort4 u;
                    u.x = f2bf(acc[mi][nj][0] + bn);
                    u.y = f2bf(acc[mi][nj][1] + bn);
                    u.z = f2bf(acc[mi][nj][2] + bn);
                    u.w = f2bf(acc[mi][nj][3] + bn);
                    *(ushort4*)(C + ((size_t)(bb * H_ + hh) * DH_ + dd) * S_ + ss) = u;
                }
            }
        }
    }
}

// ---------------------------------------------------------------------------
// bf16 MFMA flash attention — round 13: r7 kernel (84.3 µs measured) VERBATIM
// in math/pipeline/geometry, but SPLIT-S: each block processes 1024 keys
// (half = bid&1) for its 128 q-rows. Grid 1024 = 4 blocks/CU = 32 waves/CU
// (LDS 4x33.3 = 133 <= 160 KiB). Writes NORMALIZED partial O (bf16) + (m,l)
// per q-row; combine_kernel merges (flash-decode). Same double-buffer
// 2-barrier QK-one-ahead pipeline, race-free proof unchanged.
// ---------------------------------------------------------------------------
__global__ __launch_bounds__(512) void attn_mfma_kernel(
    const short* __restrict__ Qb, const short* __restrict__ Kb,
    const short* __restrict__ Vt, const int* __restrict__ vmask,
    ushort* __restrict__ Op0, ushort* __restrict__ Op1,
    float2* __restrict__ ml)
{
    __shared__ short Ks[2][64 * 64];
    __shared__ short Vs[2][64 * 64];
    __shared__ float bias_s[2][64];

    const int tid  = threadIdx.x;
    const int lane = tid & 63;
    const int w    = tid >> 6;        // 0..7
    const int c    = lane & 15;
    const int g    = lane >> 4;

    const int bid = blockIdx.x;       // ((b*16 + h)*16 + qc)*2 + half
    const int half = bid & 1;
    const int qc = (bid >> 1) & 15;
    const int h  = (bid >> 5) & 15;
    const int b  = bid >> 9;
    const int s0 = qc * 128;
    const int kts = half * 16;        // first key-tile of this half

    // Q fragments (B-operand): lane holds Q[q = lane&15][k = g*8 + j]
    bf16x8 qf[2];
    {
        const size_t qbase = ((size_t)(b * S_ + s0 + w * 16 + c)) * DM_ + h * DH_ + g * 8;
        qf[0] = *(const bf16x8*)(Qb + qbase);
        qf[1] = *(const bf16x8*)(Qb + qbase + 32);
    }

    // staging: 512 threads, one 16B chunk per thread per matrix
    const int kr0 = tid >> 3, kc0 = tid & 7;
    const size_t kpan = ((size_t)b * S_) * DM_ + h * DH_;
    const size_t vpan = ((size_t)(b * H_ + h) * DH_) * S_;

    uint4 kv0, vv0;
    int mskv = 1;

#define LOAD_TILE(KT)                                                            \
    do {                                                                         \
        kv0 = *(const uint4*)(Kb + kpan + (size_t)((KT) * 64 + kr0) * DM_ + kc0 * 8); \
        vv0 = *(const uint4*)(Vt + vpan + (size_t)kr0 * S_ + (KT) * 64 + kc0 * 8);    \
        if (tid < 64) mskv = vmask[b * S_ + (KT) * 64 + tid];                    \
    } while (0)

#define STORE_TILE(BUF)                                                          \
    do {                                                                         \
        *(uint4*)&Ks[BUF][kr0 * 64 + ((kc0 ^ (kr0 & 7)) * 8)] = kv0;             \
        *(uint4*)&Vs[BUF][kr0 * 64 + ((kc0 ^ (kr0 & 7)) * 8)] = vv0;             \
        if (tid < 64) bias_s[BUF][tid] = mskv ? 0.f : NEGV;                      \
    } while (0)

#define QK_TILE(ACC, BUF)                                                        \
    do {                                                                         \
        _Pragma("unroll")                                                        \
        for (int km = 0; km < 4; ++km)                                           \
            ACC[km] = *(const f32x4*)&bias_s[BUF][km * 16 + g * 4];              \
        _Pragma("unroll")                                                        \
        for (int km = 0; km < 4; ++km) {                                         \
            const int krow = km * 16 + c;                                        \
            const int swz = krow & 7;                                            \
            _Pragma("unroll")                                                    \
            for (int t2 = 0; t2 < 2; ++t2) {                                     \
                const bf16x8 kf = *(const bf16x8*)&Ks[BUF][krow * 64 +           \
                                        (((t2 * 4 + g) ^ swz) * 8)];             \
                ACC[km] = __builtin_amdgcn_mfma_f32_16x16x32_bf16(               \
                              kf, qf[t2], ACC[km], 0, 0, 0);                     \
            }                                                                    \
        }                                                                        \
    } while (0)

#define SOFTMAX_PV(ACC, BUF)                                                     \
    do {                                                                         \
        float pm = -1e30f;                                                       \
        _Pragma("unroll")                                                        \
        for (int km = 0; km < 4; ++km)                                           \
            _Pragma("unroll")                                                    \
            for (int r = 0; r < 4; ++r) pm = fmaxf(pm, ACC[km][r]);              \
        pm = fmaxf(pm, __shfl_xor(pm, 16));                                      \
        pm = fmaxf(pm, __shfl_xor(pm, 32));                                      \
        if (!__all(pm <= m_run + DEFER_THR)) {                                   \
            const float m_new = fmaxf(m_run, pm);                                \
            const float sc = exp2f(m_run - m_new);                               \
            _Pragma("unroll")                                                    \
            for (int r = 0; r < 4; ++r) {                                        \
                const float scr = __shfl(sc, (lane & 48) | (g * 4 + r));         \
                _Pragma("unroll")                                                \
                for (int dg = 0; dg < 4; ++dg) acc_o[dg][r] *= scr;              \
            }                                                                    \
            l_run *= sc;                                                         \
            m_run = m_new;                                                       \
        }                                                                        \
        float p[16];                                                             \
        float tsum = 0.f;                                                        \
        _Pragma("unroll")                                                        \
        for (int km = 0; km < 4; ++km)                                           \
            _Pragma("unroll")                                                    \
            for (int r = 0; r < 4; ++r) {                                        \
                const float e = exp2f(ACC[km][r] - m_run);                       \
                p[km * 4 + r] = e;                                               \
                tsum += e;                                                       \
            }                                                                    \
        tsum += __shfl_xor(tsum, 16);                                            \
        tsum += __shfl_xor(tsum, 32);                                            \
        l_run += tsum;                                                           \
        uint32_t pk[4][2];                                                       \
        _Pragma("unroll")                                                        \
        for (int km = 0; km < 4; ++km) {                                         \
            pk[km][0] = cvt_pk_bf16(p[km * 4 + 0], p[km * 4 + 1]);               \
            pk[km][1] = cvt_pk_bf16(p[km * 4 + 2], p[km * 4 + 3]);               \
        }                                                                        \
        _Pragma("unroll")                                                        \
        for (int t2 = 0; t2 < 2; ++t2) {                                         \
            uint32_t fw[4];                                                      \
            _Pragma("unroll")                                                    \
            for (int w2 = 0; w2 < 4; ++w2) {                                     \
                const int src = (w2 < 2) ? srcA : srcB;                          \
                const uint32_t vlo = (uint32_t)__builtin_amdgcn_ds_bpermute(     \
                    src, (int)pk[2 * t2][w2 & 1]);                               \
                const uint32_t vhi = (uint32_t)__builtin_amdgcn_ds_bpermute(     \
                    src, (int)pk[2 * t2 + 1][w2 & 1]);                           \
                fw[w2] = hiSel ? vhi : vlo;                                      \
            }                                                                    \
            union { uint32_t u[4]; bf16x8 v; } pf;                               \
            pf.u[0] = fw[0]; pf.u[1] = fw[1]; pf.u[2] = fw[2]; pf.u[3] = fw[3];  \
            _Pragma("unroll")                                                    \
            for (int dg = 0; dg < 4; ++dg) {                                     \
                const int vrow = dg * 16 + c;                                    \
                const bf16x8 vf = *(const bf16x8*)&Vs[BUF][vrow * 64 +           \
                                        (((t2 * 4 + g) ^ (vrow & 7)) * 8)];      \
                acc_o[dg] = __builtin_amdgcn_mfma_f32_16x16x32_bf16(             \
                                pf.v, vf, acc_o[dg], 0, 0, 0);                   \
            }                                                                    \
        }                                                                        \
    } while (0)

    float m_run = -1e30f, l_run = 0.f;
    f32x4 acc_o[4];
#pragma unroll
    for (int dg = 0; dg < 4; ++dg) acc_o[dg] = (f32x4){0.f, 0.f, 0.f, 0.f};

    const int srcA = ((((g & 1) * 2) << 4) + c) * 4;
    const int srcB = ((((g & 1) * 2 + 1) << 4) + c) * 4;
    const bool hiSel = (lane >= 32);

    // ---- prologue: tile kts into buf0, QK(0)
    LOAD_TILE(kts);
    STORE_TILE(0);
    __syncthreads();
    LOAD_TILE(kts + 1);
    f32x4 acc_t[4];
    QK_TILE(acc_t, 0);

    // ---- main loop over this half's 16 tiles
    for (int kt = 0; kt < 15; ++kt) {
        const int cur = kt & 1, nxt = cur ^ 1;
        STORE_TILE(nxt);                       // regs hold tile kt+1
        __syncthreads();
        if (kt + 2 < 16) LOAD_TILE(kts + kt + 2);
        f32x4 acc_n[4];
        QK_TILE(acc_n, nxt);                   // MFMA pipe: scores(kt+1)
        SOFTMAX_PV(acc_t, cur);                // VALU overlaps MFMA above
#pragma unroll
        for (int km = 0; km < 4; ++km) acc_t[km] = acc_n[km];
        __syncthreads();                       // protect buf[cur] before overwrite
    }
    SOFTMAX_PV(acc_t, 1);                      // last tile (index 15 -> buf 1)

#undef LOAD_TILE
#undef STORE_TILE
#undef QK_TILE
#undef SOFTMAX_PV

    // ---- write per-row stats (lanes g==0 hold stats for q = c) and
    //      normalized partial O (bf16)
    const float linv = (l_run > 0.f) ? (1.0f / l_run) : 0.f;
    if (g == 0) {
        const int row = s0 + w * 16 + c;
        ml[(size_t)half * (B_ * S_ * H_) + ((size_t)(b * S_ + row) * H_ + h)] =
            make_float2(m_run, l_run);
    }
    ushort* Op = half ? Op1 : Op0;
#pragma unroll
    for (int r = 0; r < 4; ++r) {
        const float lr = __shfl(linv, (lane & 48) | (g * 4 + r));
        const int row = s0 + w * 16 + g * 4 + r;
        const size_t ob = ((size_t)(b * S_ + row)) * DM_ + h * DH_;
#pragma unroll
        for (int dg = 0; dg < 4; ++dg)
            Op[ob + dg * 16 + c] = f2bf(acc_o[dg][r] * lr);
    }
}

// ---------------------------------------------------------------------------
// flash-decode merge: O = (w1*O1 + w2*O2)/(w1+w2), w_i = l_i * 2^(m_i - m)
// ---------------------------------------------------------------------------
__global__ __launch_bounds__(256) void combine_kernel(
    const ushort* __restrict__ Op0, const ushort* __restrict__ Op1,
    const float2* __restrict__ ml, ushort* __restrict__ Ob)
{
    const int tid = threadIdx.x;
    const int rho = blockIdx.x * 32 + (tid >> 3);   // (b*S+s)*16 + h
    const int d0 = (tid & 7) * 8;
    const float2 s1 = ml[rho];
    const float2 s2 = ml[B_ * S_ * H_ + rho];
    const float m = fmaxf(s1.x, s2.x);
    const float w1 = s1.y * exp2f(s1.x - m);
    const float w2 = s2.y * exp2f(s2.x - m);
    const float inv = 1.0f / (w1 + w2);
    const float a1 = w1 * inv, a2 = w2 * inv;
    const int bs = rho >> 4, h = rho & 15;
    const size_t off = (size_t)bs * DM_ + h * DH_ + d0;
    union { uint4 u; ushort s[8]; } p1, p2, o;
    p1.u = *(const uint4*)(Op0 + off);
    p2.u = *(const uint4*)(Op1 + off);
#pragma unroll
    for (int j = 0; j < 8; ++j) {
        const float v1 = __uint_as_float((uint32_t)p1.s[j] << 16);
        const float v2 = __uint_as_float((uint32_t)p2.s[j] << 16);
        o.s[j] = f2bf(a1 * v1 + a2 * v2);
    }
    *(uint4*)(Ob + off) = o.u;
}

// ---------------------------------------------------------------------------
extern "C" void kernel_launch(void* const* d_in, const int* in_sizes, int n_in,
                              void* d_out, int out_size, void* d_ws, size_t ws_size,
                              hipStream_t stream)
{
    const float* x     = (const float*)d_in[0];
    const int*   vmask = (const int*)d_in[1];
    const float* pos   = (const float*)d_in[2];
    const float* Wq    = (const float*)d_in[3];
    const float* bq    = (const float*)d_in[4];
    const float* Wk    = (const float*)d_in[5];
    const float* bk    = (const float*)d_in[6];
    const float* Wv    = (const float*)d_in[7];
    const float* bv    = (const float*)d_in[8];
    const float* Wo    = (const float*)d_in[9];
    const float* bo    = (const float*)d_in[10];
    float* out = (float*)d_out;

    const size_t MN = (size_t)(B_ * S_) * (H_ * DH_);   // 4M elems

    ushort* xb  = (ushort*)d_ws;          // 8 MB   [dead after QKV -> reused as Op0]
    ushort* Wtq = xb + MN;                // 2 MB each
    ushort* Wtk = Wtq + 1024 * 1024;
    ushort* Wtv = Wtk + 1024 * 1024;
    ushort* Wto = Wtv + 1024 * 1024;
    ushort* Qb  = Wto + 1024 * 1024;      // 8 MB each
    ushort* Kb  = Qb + MN;
    ushort* Vt  = Kb + MN;
    ushort* Ob  = Vt + MN;                // 8 MB (offset 40..48 MB)
    ushort* Op1 = Ob + MN;                // 8 MB (48..56 MB)
    float2* ml  = (float2*)(Op1 + MN);    // 1 MB (56..57 MB)
    ushort* Op0 = xb;                     // reuse: xb dead after QKV gemm

    // merged prep: x conversion (2048 blocks) + 4 weight transposes (1024)
    prep_kernel<<<3072, 256, 0, stream>>>(x, xb, Wq, Wk, Wv, Wo,
                                          Wtq, Wtk, Wtv, Wto);

    // fused QKV: grid = (4096/128) m-tiles x 24 n-tiles = 768 blocks (3/CU)
    gemm_bf16<1><<<768, 256, 0, stream>>>(xb, Wtq, Wtk, Wtv, bq, bk, bv, pos,
                                          (void*)Qb, (void*)Kb, (void*)Vt);

    // attention: 1024 blocks x 512 threads (128 q x 1024 keys each, 4/CU)
    attn_mfma_kernel<<<B_ * H_ * (S_ / 128) * 2, 512, 0, stream>>>(
        (const short*)Qb, (const short*)Kb, (const short*)Vt, vmask,
        Op0, Op1, ml);

    // merge partials: 65536 rows / 32 per block = 2048 blocks
    combine_kernel<<<2048, 256, 0, stream>>>(Op0, Op1, ml, Ob);

    // out-proj: grid = (4096/64) x 8 = 512 blocks (2/CU)
    gemm_bf16<0><<<512, 256, 0, stream>>>(Ob, Wto, nullptr, nullptr, bo, nullptr, nullptr,
                                          nullptr, (void*)out, nullptr, nullptr);
}

// Round 14
// 170.686 us; speedup vs baseline: 1.4883x; 1.0320x over previous
//
#include <hip/hip_runtime.h>
#include <cstddef>
#include <cstdint>

#define B_ 2
#define S_ 2048
#define DM_ 1024
#define H_ 16
#define DH_ 64
#define NEGV (-1e12f)
// log2(e) / sqrt(DH) folded into Q at projection epilogue
#define QSCALE 0.18033688011112042f
// defer-max threshold in log2 units: P <= 2^12 -> fp32-safe
#define DEFER_THR 12.0f

typedef __attribute__((ext_vector_type(8))) short bf16x8;
typedef __attribute__((ext_vector_type(4))) float f32x4;

__device__ __forceinline__ unsigned short f2bf(float f) {
    union { float f; uint32_t u; } v; v.f = f;
    uint32_t u = v.u;
    u += 0x7FFF + ((u >> 16) & 1);   // round-to-nearest-even
    return (unsigned short)(u >> 16);
}

// packed f32x2 -> bf16x2 (RNE), single HW instruction (T12 recipe)
__device__ __forceinline__ uint32_t cvt_pk_bf16(float lo, float hi) {
    uint32_t r;
    asm volatile("v_cvt_pk_bf16_f32 %0, %1, %2" : "=v"(r) : "v"(lo), "v"(hi));
    return r;
}

__device__ __forceinline__ void gload_lds16(const void* g, void* l) {
    __builtin_amdgcn_global_load_lds(
        (__attribute__((address_space(1))) void*)g,
        (__attribute__((address_space(3))) void*)l,
        16, 0, 0);
}

// ---------------------------------------------------------------------------
// merged prep: blocks [0,2048): x fp32 -> bf16; blocks [2048,3072): W
// transpose+convert (validated r12/r13)
// ---------------------------------------------------------------------------
__global__ __launch_bounds__(256) void prep_kernel(
    const float* __restrict__ x, ushort* __restrict__ xb,
    const float* __restrict__ W0, const float* __restrict__ W1,
    const float* __restrict__ W2, const float* __restrict__ W3,
    ushort* __restrict__ T0, ushort* __restrict__ T1,
    ushort* __restrict__ T2, ushort* __restrict__ T3)
{
    __shared__ float T[64][65];
    const int tid = threadIdx.x;
    if (blockIdx.x < 2048) {
        const size_t i = ((size_t)blockIdx.x * 256 + tid) * 8;
        const float4 a = *(const float4*)(x + i);
        const float4 b = *(const float4*)(x + i + 4);
        ushort4 u0, u1;
        u0.x = f2bf(a.x); u0.y = f2bf(a.y); u0.z = f2bf(a.z); u0.w = f2bf(a.w);
        u1.x = f2bf(b.x); u1.y = f2bf(b.y); u1.z = f2bf(b.z); u1.w = f2bf(b.w);
        *(ushort4*)(xb + i) = u0;
        *(ushort4*)(xb + i + 4) = u1;
        return;
    }
    const int bid = blockIdx.x - 2048;
    const int sel = bid >> 8;
    const int bt  = bid & 255;
    const float* W = (sel == 0) ? W0 : (sel == 1) ? W1 : (sel == 2) ? W2 : W3;
    ushort* Wt = (sel == 0) ? T0 : (sel == 1) ? T1 : (sel == 2) ? T2 : T3;

    const int n0 = (bt & 15) * 64;
    const int k0 = (bt >> 4) * 64;
    const int tr = tid >> 4, tc = tid & 15;
#pragma unroll
    for (int i = 0; i < 4; ++i) {
        const float4 v = *(const float4*)(W + (size_t)(k0 + tr + i * 16) * 1024 + n0 + tc * 4);
        T[tr + i * 16][tc * 4 + 0] = v.x;
        T[tr + i * 16][tc * 4 + 1] = v.y;
        T[tr + i * 16][tc * 4 + 2] = v.z;
        T[tr + i * 16][tc * 4 + 3] = v.w;
    }
    __syncthreads();
    const int orr = tid >> 2, oc = tid & 3;
#pragma unroll
    for (int j = 0; j < 4; ++j) {
        ushort4 u;
        u.x = f2bf(T[oc * 16 + j * 4 + 0][orr]);
        u.y = f2bf(T[oc * 16 + j * 4 + 1][orr]);
        u.z = f2bf(T[oc * 16 + j * 4 + 2][orr]);
        u.w = f2bf(T[oc * 16 + j * 4 + 3][orr]);
        *(ushort4*)(Wt + (size_t)(n0 + orr) * 1024 + k0 + oc * 16 + j * 4) = u;
    }
}

// ---------------------------------------------------------------------------
// bf16 MFMA GEMM, C = A @ Bt^T (+bias, +epilogue). A[M][1024], Bt[n][1024].
// MODE 1: fused QKV (BM=128, Ntot=3072 in 3 segments; rope epilogues, V transp)
// MODE 0: out-proj  (BM=64, N=1024, fp32 out)
// (unchanged — validated)
// ---------------------------------------------------------------------------
template <int MODE>
__global__ __launch_bounds__(256) void gemm_bf16(
    const ushort* __restrict__ A,
    const ushort* __restrict__ B0, const ushort* __restrict__ B1, const ushort* __restrict__ B2,
    const float* __restrict__ bias0, const float* __restrict__ bias1, const float* __restrict__ bias2,
    const float* __restrict__ pos,
    void* __restrict__ o0, void* __restrict__ o1, void* __restrict__ o2)
{
    constexpr int BM = MODE ? 128 : 64;
    constexpr int BN = 128;
    constexpr int NTN = MODE ? 24 : 8;
    constexpr int A_ISS = BM / 64;
    constexpr int ABYTES = BM * 64;
    constexpr int WM = MODE ? 2 : 1;
    constexpr int TM = BM / WM;
    constexpr int TN = BN / (4 / WM);
    constexpr int MI = TM / 16;
    constexpr int NJ = TN / 16;
    constexpr int NT = DM_ / 32;

    __shared__ char lds[2][(BM + BN) * 64];

    const int tid  = threadIdx.x;
    const int lane = tid & 63;
    const int lc = lane & 15, lg = lane >> 4;
    const int w  = tid >> 6;
    const int wm = MODE ? (w >> 1) : 0;
    const int wn = MODE ? (w & 1) : w;

    const int ntile = blockIdx.x % NTN;
    const int mtile = blockIdx.x / NTN;
    const int m0 = mtile * BM;

    int seg = 0, nseg0 = ntile * 128;
    const ushort* Bt = B0;
    const float* biasp = bias0;
    if constexpr (MODE == 1) {
        seg = ntile >> 3;
        nseg0 = (ntile & 7) * 128;
        Bt = (seg == 0) ? B0 : (seg == 1) ? B1 : B2;
        biasp = (seg == 0) ? bias0 : (seg == 1) ? bias1 : bias2;
    }

    const int sr = tid >> 2;
    const int sc = (tid & 3) * 8;
    const int wub = (tid & 0xC0) * 16;

#define STAGE(BUF, KT)                                                             \
    do {                                                                           \
        const int k0s = (KT) * 32;                                                 \
        char* lb = &lds[BUF][0];                                                   \
        _Pragma("unroll")                                                          \
        for (int ii = 0; ii < A_ISS; ++ii)                                         \
            gload_lds16(A + (size_t)(m0 + ii * 64 + sr) * DM_ + k0s + sc,          \
                        lb + ii * 4096 + wub);                                     \
        _Pragma("unroll")                                                          \
        for (int ii = 0; ii < 2; ++ii)                                             \
            gload_lds16(Bt + (size_t)(nseg0 + ii * 64 + sr) * DM_ + k0s + sc,      \
                        lb + ABYTES + ii * 4096 + wub);                            \
    } while (0)

    f32x4 acc[MI][NJ];
#pragma unroll
    for (int mi = 0; mi < MI; ++mi)
#pragma unroll
        for (int nj = 0; nj < NJ; ++nj) acc[mi][nj] = (f32x4){0.f, 0.f, 0.f, 0.f};

    STAGE(0, 0);

    for (int kt = 0; kt < NT; ++kt) {
        const int cur = kt & 1;
        __syncthreads();
        if (kt + 1 < NT) STAGE(cur ^ 1, kt + 1);
        const char* Ab = &lds[cur][0];
        const char* Bb = Ab + ABYTES;
        bf16x8 af[MI], bfr[NJ];
#pragma unroll
        for (int mi = 0; mi < MI; ++mi)
            af[mi] = *(const bf16x8*)(Ab + (wm * TM + mi * 16 + lc) * 64 + lg * 16);
#pragma unroll
        for (int nj = 0; nj < NJ; ++nj)
            bfr[nj] = *(const bf16x8*)(Bb + (wn * TN + nj * 16 + lc) * 64 + lg * 16);
#pragma unroll
        for (int mi = 0; mi < MI; ++mi)
#pragma unroll
            for (int nj = 0; nj < NJ; ++nj)
                acc[mi][nj] = __builtin_amdgcn_mfma_f32_16x16x32_bf16(af[mi], bfr[nj], acc[mi][nj], 0, 0, 0);
    }
#undef STAGE

    if constexpr (MODE == 0) {
        float* C = (float*)o0;
#pragma unroll
        for (int nj = 0; nj < NJ; ++nj) {
            const int n = nseg0 + wn * TN + nj * 16 + lc;
            const float bn = biasp[n];
#pragma unroll
            for (int mi = 0; mi < MI; ++mi)
#pragma unroll
                for (int r = 0; r < 4; ++r) {
                    const int m = m0 + wm * TM + mi * 16 + lg * 4 + r;
                    C[(size_t)m * DM_ + n] = acc[mi][nj][r] + bn;
                }
        }
    } else {
        if (seg < 2) {
            ushort* C = (seg == 0) ? (ushort*)o0 : (ushort*)o1;
#pragma unroll
            for (int nj = 0; nj < NJ; ++nj) {
                const int n = nseg0 + wn * TN + nj * 16 + lc;
                const float bn = biasp[n];
                const int i2 = (n & 63) & ~1;
                const bool odd = (n & 1) != 0;
#pragma unroll
                for (int mi = 0; mi < MI; ++mi)
#pragma unroll
                    for (int r = 0; r < 4; ++r) {
                        const int m = m0 + wm * TM + mi * 16 + lg * 4 + r;
                        const int s = m & (S_ - 1);
                        const float2 pz = *(const float2*)(pos + (size_t)s * DH_ + i2);
                        const float v = acc[mi][nj][r] + bn;
                        const float pv = __shfl_xor(v, 1);
                        float ov = odd ? (v * pz.y + pv * pz.x) : (v * pz.y - pv * pz.x);
                        if (seg == 0) ov *= QSCALE;
                        C[(size_t)m * (H_ * DH_) + n] = f2bf(ov);
                    }
            }
        } else {
            ushort* C = (ushort*)o2;
#pragma unroll
            for (int nj = 0; nj < NJ; ++nj) {
                const int n = nseg0 + wn * TN + nj * 16 + lc;
                const int hh = n >> 6, dd = n & 63;
                const float bn = biasp[n];
#pragma unroll
                for (int mi = 0; mi < MI; ++mi) {
                    const int mb = m0 + wm * TM + mi * 16 + lg * 4;
                    const int bb = mb >> 11, ss = mb & (S_ - 1);
                    ushort4 u;
                    u.x = f2bf(acc[mi][nj][0] + bn);
                    u.y = f2bf(acc[mi][nj][1] + bn);
                    u.z = f2bf(acc[mi][nj][2] + bn);
                    u.w = f2bf(acc[mi][nj][3] + bn);
                    *(ushort4*)(C + ((size_t)(bb * H_ + hh) * DH_ + dd) * S_ + ss) = u;
                }
            }
        }
    }
}

// ---------------------------------------------------------------------------
// bf16 MFMA flash attention — round 14: the round-7 kernel VERBATIM (best
// measured: 84.3 µs). 8 waves x 16 q = 128 q/block, 512 thr, grid 512 =
// 2 blocks/CU. K/V double-buffered LDS (XOR-swizzled), QK^T pipelined one
// tile ahead, defer-max, cvt_pk packing, bpermute P-redistribution.
// ---------------------------------------------------------------------------
__global__ __launch_bounds__(512) void attn_mfma_kernel(
    const short* __restrict__ Qb, const short* __restrict__ Kb,
    const short* __restrict__ Vt, const int* __restrict__ vmask,
    ushort* __restrict__ O)
{
    __shared__ short Ks[2][64 * 64];
    __shared__ short Vs[2][64 * 64];
    __shared__ float bias_s[2][64];

    const int tid  = threadIdx.x;
    const int lane = tid & 63;
    const int w    = tid >> 6;        // 0..7
    const int c    = lane & 15;
    const int g    = lane >> 4;

    const int bid = blockIdx.x;       // b*256 + h*16 + qc  (qc low: L2 reuse)
    const int qc = bid & 15;
    const int h  = (bid >> 4) & 15;
    const int b  = bid >> 8;
    const int s0 = qc * 128;

    // Q fragments (B-operand): lane holds Q[q = lane&15][k = g*8 + j]
    bf16x8 qf[2];
    {
        const size_t qbase = ((size_t)(b * S_ + s0 + w * 16 + c)) * DM_ + h * DH_ + g * 8;
        qf[0] = *(const bf16x8*)(Qb + qbase);
        qf[1] = *(const bf16x8*)(Qb + qbase + 32);
    }

    // staging: 512 threads, one 16B chunk per thread per matrix
    const int kr0 = tid >> 3, kc0 = tid & 7;
    const size_t kpan = ((size_t)b * S_) * DM_ + h * DH_;
    const size_t vpan = ((size_t)(b * H_ + h) * DH_) * S_;

    uint4 kv0, vv0;
    int mskv = 1;
    constexpr int NT = S_ / 64;

#define LOAD_TILE(KT)                                                            \
    do {                                                                         \
        kv0 = *(const uint4*)(Kb + kpan + (size_t)((KT) * 64 + kr0) * DM_ + kc0 * 8); \
        vv0 = *(const uint4*)(Vt + vpan + (size_t)kr0 * S_ + (KT) * 64 + kc0 * 8);    \
        if (tid < 64) mskv = vmask[b * S_ + (KT) * 64 + tid];                    \
    } while (0)

#define STORE_TILE(BUF)                                                          \
    do {                                                                         \
        *(uint4*)&Ks[BUF][kr0 * 64 + ((kc0 ^ (kr0 & 7)) * 8)] = kv0;             \
        *(uint4*)&Vs[BUF][kr0 * 64 + ((kc0 ^ (kr0 & 7)) * 8)] = vv0;             \
        if (tid < 64) bias_s[BUF][tid] = mskv ? 0.f : NEGV;                      \
    } while (0)

// QK^T (swapped): ACC[km] = S^T[key][q=c], init with mask bias
#define QK_TILE(ACC, BUF)                                                        \
    do {                                                                         \
        _Pragma("unroll")                                                        \
        for (int km = 0; km < 4; ++km)                                           \
            ACC[km] = *(const f32x4*)&bias_s[BUF][km * 16 + g * 4];              \
        _Pragma("unroll")                                                        \
        for (int km = 0; km < 4; ++km) {                                         \
            const int krow = km * 16 + c;                                        \
            const int swz = krow & 7;                                            \
            _Pragma("unroll")                                                    \
            for (int t2 = 0; t2 < 2; ++t2) {                                     \
                const bf16x8 kf = *(const bf16x8*)&Ks[BUF][krow * 64 +           \
                                        (((t2 * 4 + g) ^ swz) * 8)];             \
                ACC[km] = __builtin_amdgcn_mfma_f32_16x16x32_bf16(               \
                              kf, qf[t2], ACC[km], 0, 0, 0);                     \
            }                                                                    \
        }                                                                        \
    } while (0)

// softmax (defer-max) + P->bf16 + bpermute redistribution + PV from Vs[BUF]
#define SOFTMAX_PV(ACC, BUF)                                                     \
    do {                                                                         \
        float pm = -1e30f;                                                       \
        _Pragma("unroll")                                                        \
        for (int km = 0; km < 4; ++km)                                           \
            _Pragma("unroll")                                                    \
            for (int r = 0; r < 4; ++r) pm = fmaxf(pm, ACC[km][r]);              \
        pm = fmaxf(pm, __shfl_xor(pm, 16));                                      \
        pm = fmaxf(pm, __shfl_xor(pm, 32));                                      \
        if (!__all(pm <= m_run + DEFER_THR)) {                                   \
            const float m_new = fmaxf(m_run, pm);                                \
            const float sc = exp2f(m_run - m_new);                               \
            _Pragma("unroll")                                                    \
            for (int r = 0; r < 4; ++r) {                                        \
                const float scr = __shfl(sc, (lane & 48) | (g * 4 + r));         \
                _Pragma("unroll")                                                \
                for (int dg = 0; dg < 4; ++dg) acc_o[dg][r] *= scr;              \
            }                                                                    \
            l_run *= sc;                                                         \
            m_run = m_new;                                                       \
        }                                                                        \
        float p[16];                                                             \
        float tsum = 0.f;                                                        \
        _Pragma("unroll")                                                        \
        for (int km = 0; km < 4; ++km)                                           \
            _Pragma("unroll")                                                    \
            for (int r = 0; r < 4; ++r) {                                        \
                const float e = exp2f(ACC[km][r] - m_run);                       \
                p[km * 4 + r] = e;                                               \
                tsum += e;                                                       \
            }                                                                    \
        tsum += __shfl_xor(tsum, 16);                                            \
        tsum += __shfl_xor(tsum, 32);                                            \
        l_run += tsum;                                                           \
        uint32_t pk[4][2];                                                       \
        _Pragma("unroll")                                                        \
        for (int km = 0; km < 4; ++km) {                                         \
            pk[km][0] = cvt_pk_bf16(p[km * 4 + 0], p[km * 4 + 1]);               \
            pk[km][1] = cvt_pk_bf16(p[km * 4 + 2], p[km * 4 + 3]);               \
        }                                                                        \
        _Pragma("unroll")                                                        \
        for (int t2 = 0; t2 < 2; ++t2) {                                         \
            uint32_t fw[4];                                                      \
            _Pragma("unroll")                                                    \
            for (int w2 = 0; w2 < 4; ++w2) {                                     \
                const int src = (w2 < 2) ? srcA : srcB;                          \
                const uint32_t vlo = (uint32_t)__builtin_amdgcn_ds_bpermute(     \
                    src, (int)pk[2 * t2][w2 & 1]);                               \
                const uint32_t vhi = (uint32_t)__builtin_amdgcn_ds_bpermute(     \
                    src, (int)pk[2 * t2 + 1][w2 & 1]);                           \
                fw[w2] = hiSel ? vhi : vlo;                                      \
            }                                                                    \
            union { uint32_t u[4]; bf16x8 v; } pf;                               \
            pf.u[0] = fw[0]; pf.u[1] = fw[1]; pf.u[2] = fw[2]; pf.u[3] = fw[3];  \
            _Pragma("unroll")                                                    \
            for (int dg = 0; dg < 4; ++dg) {                                     \
                const int vrow = dg * 16 + c;                                    \
                const bf16x8 vf = *(const bf16x8*)&Vs[BUF][vrow * 64 +           \
                                        (((t2 * 4 + g) ^ (vrow & 7)) * 8)];      \
                acc_o[dg] = __builtin_amdgcn_mfma_f32_16x16x32_bf16(             \
                                pf.v, vf, acc_o[dg], 0, 0, 0);                   \
            }                                                                    \
        }                                                                        \
    } while (0)

    float m_run = -1e30f, l_run = 0.f;
    f32x4 acc_o[4];
#pragma unroll
    for (int dg = 0; dg < 4; ++dg) acc_o[dg] = (f32x4){0.f, 0.f, 0.f, 0.f};

    const int srcA = ((((g & 1) * 2) << 4) + c) * 4;
    const int srcB = ((((g & 1) * 2 + 1) << 4) + c) * 4;
    const bool hiSel = (lane >= 32);

    // ---- prologue: tile 0 into buf0, QK(0)
    LOAD_TILE(0);
    STORE_TILE(0);
    __syncthreads();
    LOAD_TILE(1);
    f32x4 acc_t[4];
    QK_TILE(acc_t, 0);

    // ---- main loop: iteration kt issues QK(kt+1), finishes tile kt
    for (int kt = 0; kt < NT - 1; ++kt) {
        const int cur = kt & 1, nxt = cur ^ 1;
        STORE_TILE(nxt);                       // regs hold tile kt+1
        __syncthreads();
        if (kt + 2 < NT) LOAD_TILE(kt + 2);    // prefetch tile kt+2 into regs
        f32x4 acc_n[4];
        QK_TILE(acc_n, nxt);                   // MFMA pipe: scores(kt+1)
        SOFTMAX_PV(acc_t, cur);                // VALU overlaps MFMA above
#pragma unroll
        for (int km = 0; km < 4; ++km) acc_t[km] = acc_n[km];
        __syncthreads();                       // protect buf[cur] before overwrite
    }
    // ---- epilogue: finish last tile
    SOFTMAX_PV(acc_t, (NT - 1) & 1);

#undef LOAD_TILE
#undef STORE_TILE
#undef QK_TILE
#undef SOFTMAX_PV

    // ---- normalize and write O (bf16)
    const float linv = 1.0f / l_run;
#pragma unroll
    for (int r = 0; r < 4; ++r) {
        const float lr = __shfl(linv, (lane & 48) | (g * 4 + r));
        const int row = s0 + w * 16 + g * 4 + r;
        const size_t ob = ((size_t)(b * S_ + row)) * DM_ + h * DH_;
#pragma unroll
        for (int dg = 0; dg < 4; ++dg)
            O[ob + dg * 16 + c] = f2bf(acc_o[dg][r] * lr);
    }
}

// ---------------------------------------------------------------------------
extern "C" void kernel_launch(void* const* d_in, const int* in_sizes, int n_in,
                              void* d_out, int out_size, void* d_ws, size_t ws_size,
                              hipStream_t stream)
{
    const float* x     = (const float*)d_in[0];
    const int*   vmask = (const int*)d_in[1];
    const float* pos   = (const float*)d_in[2];
    const float* Wq    = (const float*)d_in[3];
    const float* bq    = (const float*)d_in[4];
    const float* Wk    = (const float*)d_in[5];
    const float* bk    = (const float*)d_in[6];
    const float* Wv    = (const float*)d_in[7];
    const float* bv    = (const float*)d_in[8];
    const float* Wo    = (const float*)d_in[9];
    const float* bo    = (const float*)d_in[10];
    float* out = (float*)d_out;

    const size_t MN = (size_t)(B_ * S_) * (H_ * DH_);   // 4M elems

    ushort* xb  = (ushort*)d_ws;          // 8 MB
    ushort* Wtq = xb + MN;                // 2 MB each
    ushort* Wtk = Wtq + 1024 * 1024;
    ushort* Wtv = Wtk + 1024 * 1024;
    ushort* Wto = Wtv + 1024 * 1024;
    ushort* Qb  = Wto + 1024 * 1024;      // 8 MB each
    ushort* Kb  = Qb + MN;
    ushort* Vt  = Kb + MN;
    ushort* Ob  = Vt + MN;

    // merged prep: x conversion (2048 blocks) + 4 weight transposes (1024)
    prep_kernel<<<3072, 256, 0, stream>>>(x, xb, Wq, Wk, Wv, Wo,
                                          Wtq, Wtk, Wtv, Wto);

    // fused QKV: grid = (4096/128) m-tiles x 24 n-tiles = 768 blocks (3/CU)
    gemm_bf16<1><<<768, 256, 0, stream>>>(xb, Wtq, Wtk, Wtv, bq, bk, bv, pos,
                                          (void*)Qb, (void*)Kb, (void*)Vt);

    // attention: 512 blocks x 512 threads (128 q-rows/block, 2 blocks/CU)
    attn_mfma_kernel<<<B_ * H_ * (S_ / 128), 512, 0, stream>>>(
        (const short*)Qb, (const short*)Kb, (const short*)Vt, vmask, Ob);

    // out-proj: grid = (4096/64) x 8 = 512 blocks (2/CU)
    gemm_bf16<0><<<512, 256, 0, stream>>>(Ob, Wto, nullptr, nullptr, bo, nullptr, nullptr,
                                          nullptr, (void*)out, nullptr, nullptr);
}

// Round 15
// 163.492 us; speedup vs baseline: 1.5538x; 1.0440x over previous
//
#include <hip/hip_runtime.h>
#include <cstddef>
#include <cstdint>

#define B_ 2
#define S_ 2048
#define DM_ 1024
#define H_ 16
#define DH_ 64
#define NEGV (-1e12f)
// log2(e) / sqrt(DH) folded into Q at projection epilogue
#define QSCALE 0.18033688011112042f
// defer-max threshold in log2 units: P <= 2^12 -> fp32-safe
#define DEFER_THR 12.0f

typedef __attribute__((ext_vector_type(8))) short bf16x8;
typedef __attribute__((ext_vector_type(4))) float f32x4;

__device__ __forceinline__ unsigned short f2bf(float f) {
    union { float f; uint32_t u; } v; v.f = f;
    uint32_t u = v.u;
    u += 0x7FFF + ((u >> 16) & 1);   // round-to-nearest-even
    return (unsigned short)(u >> 16);
}

// packed f32x2 -> bf16x2 (RNE), single HW instruction (T12 recipe)
__device__ __forceinline__ uint32_t cvt_pk_bf16(float lo, float hi) {
    uint32_t r;
    asm volatile("v_cvt_pk_bf16_f32 %0, %1, %2" : "=v"(r) : "v"(lo), "v"(hi));
    return r;
}

__device__ __forceinline__ void gload_lds16(const void* g, void* l) {
    __builtin_amdgcn_global_load_lds(
        (__attribute__((address_space(1))) void*)g,
        (__attribute__((address_space(3))) void*)l,
        16, 0, 0);
}

// ---------------------------------------------------------------------------
// merged prep: blocks [0,2048): x fp32 -> bf16; blocks [2048,3072): W
// transpose+convert (validated r12/r13)
// ---------------------------------------------------------------------------
__global__ __launch_bounds__(256) void prep_kernel(
    const float* __restrict__ x, ushort* __restrict__ xb,
    const float* __restrict__ W0, const float* __restrict__ W1,
    const float* __restrict__ W2, const float* __restrict__ W3,
    ushort* __restrict__ T0, ushort* __restrict__ T1,
    ushort* __restrict__ T2, ushort* __restrict__ T3)
{
    __shared__ float T[64][65];
    const int tid = threadIdx.x;
    if (blockIdx.x < 2048) {
        const size_t i = ((size_t)blockIdx.x * 256 + tid) * 8;
        const float4 a = *(const float4*)(x + i);
        const float4 b = *(const float4*)(x + i + 4);
        ushort4 u0, u1;
        u0.x = f2bf(a.x); u0.y = f2bf(a.y); u0.z = f2bf(a.z); u0.w = f2bf(a.w);
        u1.x = f2bf(b.x); u1.y = f2bf(b.y); u1.z = f2bf(b.z); u1.w = f2bf(b.w);
        *(ushort4*)(xb + i) = u0;
        *(ushort4*)(xb + i + 4) = u1;
        return;
    }
    const int bid = blockIdx.x - 2048;
    const int sel = bid >> 8;
    const int bt  = bid & 255;
    const float* W = (sel == 0) ? W0 : (sel == 1) ? W1 : (sel == 2) ? W2 : W3;
    ushort* Wt = (sel == 0) ? T0 : (sel == 1) ? T1 : (sel == 2) ? T2 : T3;

    const int n0 = (bt & 15) * 64;
    const int k0 = (bt >> 4) * 64;
    const int tr = tid >> 4, tc = tid & 15;
#pragma unroll
    for (int i = 0; i < 4; ++i) {
        const float4 v = *(const float4*)(W + (size_t)(k0 + tr + i * 16) * 1024 + n0 + tc * 4);
        T[tr + i * 16][tc * 4 + 0] = v.x;
        T[tr + i * 16][tc * 4 + 1] = v.y;
        T[tr + i * 16][tc * 4 + 2] = v.z;
        T[tr + i * 16][tc * 4 + 3] = v.w;
    }
    __syncthreads();
    const int orr = tid >> 2, oc = tid & 3;
#pragma unroll
    for (int j = 0; j < 4; ++j) {
        ushort4 u;
        u.x = f2bf(T[oc * 16 + j * 4 + 0][orr]);
        u.y = f2bf(T[oc * 16 + j * 4 + 1][orr]);
        u.z = f2bf(T[oc * 16 + j * 4 + 2][orr]);
        u.w = f2bf(T[oc * 16 + j * 4 + 3][orr]);
        *(ushort4*)(Wt + (size_t)(n0 + orr) * 1024 + k0 + oc * 16 + j * 4) = u;
    }
}

// ---------------------------------------------------------------------------
// bf16 MFMA GEMM, C = A @ Bt^T (+bias, +epilogue). A[M][1024], Bt[n][1024].
// MODE 1: fused QKV (BM=128, Ntot=3072 in 3 segments; rope epilogues, V transp)
// MODE 0: out-proj  (BM=64, N=1024, fp32 out)
// r15: T1 XCD-aware block remap (lid = (bid%8)*cpx + bid/8; nwg%8==0 for
// both grids) so blocks sharing A/B panels land on one XCD's L2.
// ---------------------------------------------------------------------------
template <int MODE>
__global__ __launch_bounds__(256) void gemm_bf16(
    const ushort* __restrict__ A,
    const ushort* __restrict__ B0, const ushort* __restrict__ B1, const ushort* __restrict__ B2,
    const float* __restrict__ bias0, const float* __restrict__ bias1, const float* __restrict__ bias2,
    const float* __restrict__ pos,
    void* __restrict__ o0, void* __restrict__ o1, void* __restrict__ o2)
{
    constexpr int BM = MODE ? 128 : 64;
    constexpr int BN = 128;
    constexpr int NTN = MODE ? 24 : 8;
    constexpr int CPX = MODE ? 96 : 64;   // blocks per XCD (nwg/8)
    constexpr int A_ISS = BM / 64;
    constexpr int ABYTES = BM * 64;
    constexpr int WM = MODE ? 2 : 1;
    constexpr int TM = BM / WM;
    constexpr int TN = BN / (4 / WM);
    constexpr int MI = TM / 16;
    constexpr int NJ = TN / 16;
    constexpr int NT = DM_ / 32;

    __shared__ char lds[2][(BM + BN) * 64];

    const int tid  = threadIdx.x;
    const int lane = tid & 63;
    const int lc = lane & 15, lg = lane >> 4;
    const int w  = tid >> 6;
    const int wm = MODE ? (w >> 1) : 0;
    const int wn = MODE ? (w & 1) : w;

    // T1 XCD swizzle: physical dispatch id -> logical tile id (bijective)
    const int lid = (blockIdx.x % 8) * CPX + blockIdx.x / 8;
    const int ntile = lid % NTN;
    const int mtile = lid / NTN;
    const int m0 = mtile * BM;

    int seg = 0, nseg0 = ntile * 128;
    const ushort* Bt = B0;
    const float* biasp = bias0;
    if constexpr (MODE == 1) {
        seg = ntile >> 3;
        nseg0 = (ntile & 7) * 128;
        Bt = (seg == 0) ? B0 : (seg == 1) ? B1 : B2;
        biasp = (seg == 0) ? bias0 : (seg == 1) ? bias1 : bias2;
    }

    const int sr = tid >> 2;
    const int sc = (tid & 3) * 8;
    const int wub = (tid & 0xC0) * 16;

#define STAGE(BUF, KT)                                                             \
    do {                                                                           \
        const int k0s = (KT) * 32;                                                 \
        char* lb = &lds[BUF][0];                                                   \
        _Pragma("unroll")                                                          \
        for (int ii = 0; ii < A_ISS; ++ii)                                         \
            gload_lds16(A + (size_t)(m0 + ii * 64 + sr) * DM_ + k0s + sc,          \
                        lb + ii * 4096 + wub);                                     \
        _Pragma("unroll")                                                          \
        for (int ii = 0; ii < 2; ++ii)                                             \
            gload_lds16(Bt + (size_t)(nseg0 + ii * 64 + sr) * DM_ + k0s + sc,      \
                        lb + ABYTES + ii * 4096 + wub);                            \
    } while (0)

    f32x4 acc[MI][NJ];
#pragma unroll
    for (int mi = 0; mi < MI; ++mi)
#pragma unroll
        for (int nj = 0; nj < NJ; ++nj) acc[mi][nj] = (f32x4){0.f, 0.f, 0.f, 0.f};

    STAGE(0, 0);

    for (int kt = 0; kt < NT; ++kt) {
        const int cur = kt & 1;
        __syncthreads();
        if (kt + 1 < NT) STAGE(cur ^ 1, kt + 1);
        const char* Ab = &lds[cur][0];
        const char* Bb = Ab + ABYTES;
        bf16x8 af[MI], bfr[NJ];
#pragma unroll
        for (int mi = 0; mi < MI; ++mi)
            af[mi] = *(const bf16x8*)(Ab + (wm * TM + mi * 16 + lc) * 64 + lg * 16);
#pragma unroll
        for (int nj = 0; nj < NJ; ++nj)
            bfr[nj] = *(const bf16x8*)(Bb + (wn * TN + nj * 16 + lc) * 64 + lg * 16);
#pragma unroll
        for (int mi = 0; mi < MI; ++mi)
#pragma unroll
            for (int nj = 0; nj < NJ; ++nj)
                acc[mi][nj] = __builtin_amdgcn_mfma_f32_16x16x32_bf16(af[mi], bfr[nj], acc[mi][nj], 0, 0, 0);
    }
#undef STAGE

    if constexpr (MODE == 0) {
        float* C = (float*)o0;
#pragma unroll
        for (int nj = 0; nj < NJ; ++nj) {
            const int n = nseg0 + wn * TN + nj * 16 + lc;
            const float bn = biasp[n];
#pragma unroll
            for (int mi = 0; mi < MI; ++mi)
#pragma unroll
                for (int r = 0; r < 4; ++r) {
                    const int m = m0 + wm * TM + mi * 16 + lg * 4 + r;
                    C[(size_t)m * DM_ + n] = acc[mi][nj][r] + bn;
                }
        }
    } else {
        if (seg < 2) {
            ushort* C = (seg == 0) ? (ushort*)o0 : (ushort*)o1;
#pragma unroll
            for (int nj = 0; nj < NJ; ++nj) {
                const int n = nseg0 + wn * TN + nj * 16 + lc;
                const float bn = biasp[n];
                const int i2 = (n & 63) & ~1;
                const bool odd = (n & 1) != 0;
#pragma unroll
                for (int mi = 0; mi < MI; ++mi)
#pragma unroll
                    for (int r = 0; r < 4; ++r) {
                        const int m = m0 + wm * TM + mi * 16 + lg * 4 + r;
                        const int s = m & (S_ - 1);
                        const float2 pz = *(const float2*)(pos + (size_t)s * DH_ + i2);
                        const float v = acc[mi][nj][r] + bn;
                        const float pv = __shfl_xor(v, 1);
                        float ov = odd ? (v * pz.y + pv * pz.x) : (v * pz.y - pv * pz.x);
                        if (seg == 0) ov *= QSCALE;
                        C[(size_t)m * (H_ * DH_) + n] = f2bf(ov);
                    }
            }
        } else {
            ushort* C = (ushort*)o2;
#pragma unroll
            for (int nj = 0; nj < NJ; ++nj) {
                const int n = nseg0 + wn * TN + nj * 16 + lc;
                const int hh = n >> 6, dd = n & 63;
                const float bn = biasp[n];
#pragma unroll
                for (int mi = 0; mi < MI; ++mi) {
                    const int mb = m0 + wm * TM + mi * 16 + lg * 4;
                    const int bb = mb >> 11, ss = mb & (S_ - 1);
                    ushort4 u;
                    u.x = f2bf(acc[mi][nj][0] + bn);
                    u.y = f2bf(acc[mi][nj][1] + bn);
                    u.z = f2bf(acc[mi][nj][2] + bn);
                    u.w = f2bf(acc[mi][nj][3] + bn);
                    *(ushort4*)(C + ((size_t)(bb * H_ + hh) * DH_ + dd) * S_ + ss) = u;
                }
            }
        }
    }
}

// ---------------------------------------------------------------------------
// bf16 MFMA flash attention — round 15: round-7 kernel VERBATIM (best:
// 84-88 µs) + T1 XCD-aware block remap: the 16 blocks sharing a (b,h) K/V
// panel (512 KB) now land on ONE XCD's L2 (2-3 MB/XCD working set <= 4 MB).
// Gain channel: K/V loads hit L2 (~200cy) instead of HBM (~900cy) in a
// latency-bound kernel. Pure bijective index remap — zero correctness risk.
// ---------------------------------------------------------------------------
__global__ __launch_bounds__(512) void attn_mfma_kernel(
    const short* __restrict__ Qb, const short* __restrict__ Kb,
    const short* __restrict__ Vt, const int* __restrict__ vmask,
    ushort* __restrict__ O)
{
    __shared__ short Ks[2][64 * 64];
    __shared__ short Vs[2][64 * 64];
    __shared__ float bias_s[2][64];

    const int tid  = threadIdx.x;
    const int lane = tid & 63;
    const int w    = tid >> 6;        // 0..7
    const int c    = lane & 15;
    const int g    = lane >> 4;

    // T1 XCD swizzle (nwg=512, 64 per XCD): logical id groups the 16
    // panel-sharing blocks (same b,h) onto one XCD.
    const int bid = (blockIdx.x % 8) * 64 + blockIdx.x / 8;
    const int qc = bid & 15;
    const int h  = (bid >> 4) & 15;
    const int b  = bid >> 8;
    const int s0 = qc * 128;

    // Q fragments (B-operand): lane holds Q[q = lane&15][k = g*8 + j]
    bf16x8 qf[2];
    {
        const size_t qbase = ((size_t)(b * S_ + s0 + w * 16 + c)) * DM_ + h * DH_ + g * 8;
        qf[0] = *(const bf16x8*)(Qb + qbase);
        qf[1] = *(const bf16x8*)(Qb + qbase + 32);
    }

    // staging: 512 threads, one 16B chunk per thread per matrix
    const int kr0 = tid >> 3, kc0 = tid & 7;
    const size_t kpan = ((size_t)b * S_) * DM_ + h * DH_;
    const size_t vpan = ((size_t)(b * H_ + h) * DH_) * S_;

    uint4 kv0, vv0;
    int mskv = 1;
    constexpr int NT = S_ / 64;

#define LOAD_TILE(KT)                                                            \
    do {                                                                         \
        kv0 = *(const uint4*)(Kb + kpan + (size_t)((KT) * 64 + kr0) * DM_ + kc0 * 8); \
        vv0 = *(const uint4*)(Vt + vpan + (size_t)kr0 * S_ + (KT) * 64 + kc0 * 8);    \
        if (tid < 64) mskv = vmask[b * S_ + (KT) * 64 + tid];                    \
    } while (0)

#define STORE_TILE(BUF)                                                          \
    do {                                                                         \
        *(uint4*)&Ks[BUF][kr0 * 64 + ((kc0 ^ (kr0 & 7)) * 8)] = kv0;             \
        *(uint4*)&Vs[BUF][kr0 * 64 + ((kc0 ^ (kr0 & 7)) * 8)] = vv0;             \
        if (tid < 64) bias_s[BUF][tid] = mskv ? 0.f : NEGV;                      \
    } while (0)

// QK^T (swapped): ACC[km] = S^T[key][q=c], init with mask bias
#define QK_TILE(ACC, BUF)                                                        \
    do {                                                                         \
        _Pragma("unroll")                                                        \
        for (int km = 0; km < 4; ++km)                                           \
            ACC[km] = *(const f32x4*)&bias_s[BUF][km * 16 + g * 4];              \
        _Pragma("unroll")                                                        \
        for (int km = 0; km < 4; ++km) {                                         \
            const int krow = km * 16 + c;                                        \
            const int swz = krow & 7;                                            \
            _Pragma("unroll")                                                    \
            for (int t2 = 0; t2 < 2; ++t2) {                                     \
                const bf16x8 kf = *(const bf16x8*)&Ks[BUF][krow * 64 +           \
                                        (((t2 * 4 + g) ^ swz) * 8)];             \
                ACC[km] = __builtin_amdgcn_mfma_f32_16x16x32_bf16(               \
                              kf, qf[t2], ACC[km], 0, 0, 0);                     \
            }                                                                    \
        }                                                                        \
    } while (0)

// softmax (defer-max) + P->bf16 + bpermute redistribution + PV from Vs[BUF]
#define SOFTMAX_PV(ACC, BUF)                                                     \
    do {                                                                         \
        float pm = -1e30f;                                                       \
        _Pragma("unroll")                                                        \
        for (int km = 0; km < 4; ++km)                                           \
            _Pragma("unroll")                                                    \
            for (int r = 0; r < 4; ++r) pm = fmaxf(pm, ACC[km][r]);              \
        pm = fmaxf(pm, __shfl_xor(pm, 16));                                      \
        pm = fmaxf(pm, __shfl_xor(pm, 32));                                      \
        if (!__all(pm <= m_run + DEFER_THR)) {                                   \
            const float m_new = fmaxf(m_run, pm);                                \
            const float sc = exp2f(m_run - m_new);                               \
            _Pragma("unroll")                                                    \
            for (int r = 0; r < 4; ++r) {                                        \
                const float scr = __shfl(sc, (lane & 48) | (g * 4 + r));         \
                _Pragma("unroll")                                                \
                for (int dg = 0; dg < 4; ++dg) acc_o[dg][r] *= scr;              \
            }                                                                    \
            l_run *= sc;                                                         \
            m_run = m_new;                                                       \
        }                                                                        \
        float p[16];                                                             \
        float tsum = 0.f;                                                        \
        _Pragma("unroll")                                                        \
        for (int km = 0; km < 4; ++km)                                           \
            _Pragma("unroll")                                                    \
            for (int r = 0; r < 4; ++r) {                                        \
                const float e = exp2f(ACC[km][r] - m_run);                       \
                p[km * 4 + r] = e;                                               \
                tsum += e;                                                       \
            }                                                                    \
        tsum += __shfl_xor(tsum, 16);                                            \
        tsum += __shfl_xor(tsum, 32);                                            \
        l_run += tsum;                                                           \
        uint32_t pk[4][2];                                                       \
        _Pragma("unroll")                                                        \
        for (int km = 0; km < 4; ++km) {                                         \
            pk[km][0] = cvt_pk_bf16(p[km * 4 + 0], p[km * 4 + 1]);               \
            pk[km][1] = cvt_pk_bf16(p[km * 4 + 2], p[km * 4 + 3]);               \
        }                                                                        \
        _Pragma("unroll")                                                        \
        for (int t2 = 0; t2 < 2; ++t2) {                                         \
            uint32_t fw[4];                                                      \
            _Pragma("unroll")                                                    \
            for (int w2 = 0; w2 < 4; ++w2) {                                     \
                const int src = (w2 < 2) ? srcA : srcB;                          \
                const uint32_t vlo = (uint32_t)__builtin_amdgcn_ds_bpermute(     \
                    src, (int)pk[2 * t2][w2 & 1]);                               \
                const uint32_t vhi = (uint32_t)__builtin_amdgcn_ds_bpermute(     \
                    src, (int)pk[2 * t2 + 1][w2 & 1]);                           \
                fw[w2] = hiSel ? vhi : vlo;                                      \
            }                                                                    \
            union { uint32_t u[4]; bf16x8 v; } pf;                               \
            pf.u[0] = fw[0]; pf.u[1] = fw[1]; pf.u[2] = fw[2]; pf.u[3] = fw[3];  \
            _Pragma("unroll")                                                    \
            for (int dg = 0; dg < 4; ++dg) {                                     \
                const int vrow = dg * 16 + c;                                    \
                const bf16x8 vf = *(const bf16x8*)&Vs[BUF][vrow * 64 +           \
                                        (((t2 * 4 + g) ^ (vrow & 7)) * 8)];      \
                acc_o[dg] = __builtin_amdgcn_mfma_f32_16x16x32_bf16(             \
                                pf.v, vf, acc_o[dg], 0, 0, 0);                   \
            }                                                                    \
        }                                                                        \
    } while (0)

    float m_run = -1e30f, l_run = 0.f;
    f32x4 acc_o[4];
#pragma unroll
    for (int dg = 0; dg < 4; ++dg) acc_o[dg] = (f32x4){0.f, 0.f, 0.f, 0.f};

    const int srcA = ((((g & 1) * 2) << 4) + c) * 4;
    const int srcB = ((((g & 1) * 2 + 1) << 4) + c) * 4;
    const bool hiSel = (lane >= 32);

    // ---- prologue: tile 0 into buf0, QK(0)
    LOAD_TILE(0);
    STORE_TILE(0);
    __syncthreads();
    LOAD_TILE(1);
    f32x4 acc_t[4];
    QK_TILE(acc_t, 0);

    // ---- main loop: iteration kt issues QK(kt+1), finishes tile kt
    for (int kt = 0; kt < NT - 1; ++kt) {
        const int cur = kt & 1, nxt = cur ^ 1;
        STORE_TILE(nxt);                       // regs hold tile kt+1
        __syncthreads();
        if (kt + 2 < NT) LOAD_TILE(kt + 2);    // prefetch tile kt+2 into regs
        f32x4 acc_n[4];
        QK_TILE(acc_n, nxt);                   // MFMA pipe: scores(kt+1)
        SOFTMAX_PV(acc_t, cur);                // VALU overlaps MFMA above
#pragma unroll
        for (int km = 0; km < 4; ++km) acc_t[km] = acc_n[km];
        __syncthreads();                       // protect buf[cur] before overwrite
    }
    // ---- epilogue: finish last tile
    SOFTMAX_PV(acc_t, (NT - 1) & 1);

#undef LOAD_TILE
#undef STORE_TILE
#undef QK_TILE
#undef SOFTMAX_PV

    // ---- normalize and write O (bf16)
    const float linv = 1.0f / l_run;
#pragma unroll
    for (int r = 0; r < 4; ++r) {
        const float lr = __shfl(linv, (lane & 48) | (g * 4 + r));
        const int row = s0 + w * 16 + g * 4 + r;
        const size_t ob = ((size_t)(b * S_ + row)) * DM_ + h * DH_;
#pragma unroll
        for (int dg = 0; dg < 4; ++dg)
            O[ob + dg * 16 + c] = f2bf(acc_o[dg][r] * lr);
    }
}

// ---------------------------------------------------------------------------
extern "C" void kernel_launch(void* const* d_in, const int* in_sizes, int n_in,
                              void* d_out, int out_size, void* d_ws, size_t ws_size,
                              hipStream_t stream)
{
    const float* x     = (const float*)d_in[0];
    const int*   vmask = (const int*)d_in[1];
    const float* pos   = (const float*)d_in[2];
    const float* Wq    = (const float*)d_in[3];
    const float* bq    = (const float*)d_in[4];
    const float* Wk    = (const float*)d_in[5];
    const float* bk    = (const float*)d_in[6];
    const float* Wv    = (const float*)d_in[7];
    const float* bv    = (const float*)d_in[8];
    const float* Wo    = (const float*)d_in[9];
    const float* bo    = (const float*)d_in[10];
    float* out = (float*)d_out;

    const size_t MN = (size_t)(B_ * S_) * (H_ * DH_);   // 4M elems

    ushort* xb  = (ushort*)d_ws;          // 8 MB
    ushort* Wtq = xb + MN;                // 2 MB each
    ushort* Wtk = Wtq + 1024 * 1024;
    ushort* Wtv = Wtk + 1024 * 1024;
    ushort* Wto = Wtv + 1024 * 1024;
    ushort* Qb  = Wto + 1024 * 1024;      // 8 MB each
    ushort* Kb  = Qb + MN;
    ushort* Vt  = Kb + MN;
    ushort* Ob  = Vt + MN;

    // merged prep: x conversion (2048 blocks) + 4 weight transposes (1024)
    prep_kernel<<<3072, 256, 0, stream>>>(x, xb, Wq, Wk, Wv, Wo,
                                          Wtq, Wtk, Wtv, Wto);

    // fused QKV: grid = 768 blocks (3/CU), XCD-swizzled internally
    gemm_bf16<1><<<768, 256, 0, stream>>>(xb, Wtq, Wtk, Wtv, bq, bk, bv, pos,
                                          (void*)Qb, (void*)Kb, (void*)Vt);

    // attention: 512 blocks x 512 threads, XCD-swizzled internally
    attn_mfma_kernel<<<B_ * H_ * (S_ / 128), 512, 0, stream>>>(
        (const short*)Qb, (const short*)Kb, (const short*)Vt, vmask, Ob);

    // out-proj: grid = 512 blocks (2/CU), XCD-swizzled internally
    gemm_bf16<0><<<512, 256, 0, stream>>>(Ob, Wto, nullptr, nullptr, bo, nullptr, nullptr,
                                          nullptr, (void*)out, nullptr, nullptr);
}

// Round 16
// 162.035 us; speedup vs baseline: 1.5678x; 1.0090x over previous
//
#include <hip/hip_runtime.h>
#include <cstddef>
#include <cstdint>

#define B_ 2
#define S_ 2048
#define DM_ 1024
#define H_ 16
#define DH_ 64
#define NEGV (-1e12f)
// log2(e) / sqrt(DH) folded into Q at projection epilogue
#define QSCALE 0.18033688011112042f
// defer-max threshold in log2 units: P <= 2^12 -> fp32-safe
#define DEFER_THR 12.0f

typedef __attribute__((ext_vector_type(8))) short bf16x8;
typedef __attribute__((ext_vector_type(4))) float f32x4;

__device__ __forceinline__ unsigned short f2bf(float f) {
    union { float f; uint32_t u; } v; v.f = f;
    uint32_t u = v.u;
    u += 0x7FFF + ((u >> 16) & 1);   // round-to-nearest-even
    return (unsigned short)(u >> 16);
}

// packed f32x2 -> bf16x2 (RNE), single HW instruction (T12 recipe)
__device__ __forceinline__ uint32_t cvt_pk_bf16(float lo, float hi) {
    uint32_t r;
    asm volatile("v_cvt_pk_bf16_f32 %0, %1, %2" : "=v"(r) : "v"(lo), "v"(hi));
    return r;
}

__device__ __forceinline__ void gload_lds16(const void* g, void* l) {
    __builtin_amdgcn_global_load_lds(
        (__attribute__((address_space(1))) void*)g,
        (__attribute__((address_space(3))) void*)l,
        16, 0, 0);
}

// ---------------------------------------------------------------------------
// merged prep: blocks [0,2048): x fp32 -> bf16; blocks [2048,3072): W
// transpose+convert (validated r12/r13)
// ---------------------------------------------------------------------------
__global__ __launch_bounds__(256) void prep_kernel(
    const float* __restrict__ x, ushort* __restrict__ xb,
    const float* __restrict__ W0, const float* __restrict__ W1,
    const float* __restrict__ W2, const float* __restrict__ W3,
    ushort* __restrict__ T0, ushort* __restrict__ T1,
    ushort* __restrict__ T2, ushort* __restrict__ T3)
{
    __shared__ float T[64][65];
    const int tid = threadIdx.x;
    if (blockIdx.x < 2048) {
        const size_t i = ((size_t)blockIdx.x * 256 + tid) * 8;
        const float4 a = *(const float4*)(x + i);
        const float4 b = *(const float4*)(x + i + 4);
        ushort4 u0, u1;
        u0.x = f2bf(a.x); u0.y = f2bf(a.y); u0.z = f2bf(a.z); u0.w = f2bf(a.w);
        u1.x = f2bf(b.x); u1.y = f2bf(b.y); u1.z = f2bf(b.z); u1.w = f2bf(b.w);
        *(ushort4*)(xb + i) = u0;
        *(ushort4*)(xb + i + 4) = u1;
        return;
    }
    const int bid = blockIdx.x - 2048;
    const int sel = bid >> 8;
    const int bt  = bid & 255;
    const float* W = (sel == 0) ? W0 : (sel == 1) ? W1 : (sel == 2) ? W2 : W3;
    ushort* Wt = (sel == 0) ? T0 : (sel == 1) ? T1 : (sel == 2) ? T2 : T3;

    const int n0 = (bt & 15) * 64;
    const int k0 = (bt >> 4) * 64;
    const int tr = tid >> 4, tc = tid & 15;
#pragma unroll
    for (int i = 0; i < 4; ++i) {
        const float4 v = *(const float4*)(W + (size_t)(k0 + tr + i * 16) * 1024 + n0 + tc * 4);
        T[tr + i * 16][tc * 4 + 0] = v.x;
        T[tr + i * 16][tc * 4 + 1] = v.y;
        T[tr + i * 16][tc * 4 + 2] = v.z;
        T[tr + i * 16][tc * 4 + 3] = v.w;
    }
    __syncthreads();
    const int orr = tid >> 2, oc = tid & 3;
#pragma unroll
    for (int j = 0; j < 4; ++j) {
        ushort4 u;
        u.x = f2bf(T[oc * 16 + j * 4 + 0][orr]);
        u.y = f2bf(T[oc * 16 + j * 4 + 1][orr]);
        u.z = f2bf(T[oc * 16 + j * 4 + 2][orr]);
        u.w = f2bf(T[oc * 16 + j * 4 + 3][orr]);
        *(ushort4*)(Wt + (size_t)(n0 + orr) * 1024 + k0 + oc * 16 + j * 4) = u;
    }
}

// ---------------------------------------------------------------------------
// bf16 MFMA GEMM, C = A @ Bt^T (+bias, +epilogue). A[M][1024], Bt[n][1024].
// MODE 1: fused QKV (BM=128, Ntot=3072 in 3 segments; rope epilogues, V transp)
// MODE 0: out-proj  (BM=64, N=1024, fp32 out)
// T1 XCD-aware block remap (validated r15).
// ---------------------------------------------------------------------------
template <int MODE>
__global__ __launch_bounds__(256) void gemm_bf16(
    const ushort* __restrict__ A,
    const ushort* __restrict__ B0, const ushort* __restrict__ B1, const ushort* __restrict__ B2,
    const float* __restrict__ bias0, const float* __restrict__ bias1, const float* __restrict__ bias2,
    const float* __restrict__ pos,
    void* __restrict__ o0, void* __restrict__ o1, void* __restrict__ o2)
{
    constexpr int BM = MODE ? 128 : 64;
    constexpr int BN = 128;
    constexpr int NTN = MODE ? 24 : 8;
    constexpr int CPX = MODE ? 96 : 64;   // blocks per XCD (nwg/8)
    constexpr int A_ISS = BM / 64;
    constexpr int ABYTES = BM * 64;
    constexpr int WM = MODE ? 2 : 1;
    constexpr int TM = BM / WM;
    constexpr int TN = BN / (4 / WM);
    constexpr int MI = TM / 16;
    constexpr int NJ = TN / 16;
    constexpr int NT = DM_ / 32;

    __shared__ char lds[2][(BM + BN) * 64];

    const int tid  = threadIdx.x;
    const int lane = tid & 63;
    const int lc = lane & 15, lg = lane >> 4;
    const int w  = tid >> 6;
    const int wm = MODE ? (w >> 1) : 0;
    const int wn = MODE ? (w & 1) : w;

    // T1 XCD swizzle: physical dispatch id -> logical tile id (bijective)
    const int lid = (blockIdx.x % 8) * CPX + blockIdx.x / 8;
    const int ntile = lid % NTN;
    const int mtile = lid / NTN;
    const int m0 = mtile * BM;

    int seg = 0, nseg0 = ntile * 128;
    const ushort* Bt = B0;
    const float* biasp = bias0;
    if constexpr (MODE == 1) {
        seg = ntile >> 3;
        nseg0 = (ntile & 7) * 128;
        Bt = (seg == 0) ? B0 : (seg == 1) ? B1 : B2;
        biasp = (seg == 0) ? bias0 : (seg == 1) ? bias1 : bias2;
    }

    const int sr = tid >> 2;
    const int sc = (tid & 3) * 8;
    const int wub = (tid & 0xC0) * 16;

#define STAGE(BUF, KT)                                                             \
    do {                                                                           \
        const int k0s = (KT) * 32;                                                 \
        char* lb = &lds[BUF][0];                                                   \
        _Pragma("unroll")                                                          \
        for (int ii = 0; ii < A_ISS; ++ii)                                         \
            gload_lds16(A + (size_t)(m0 + ii * 64 + sr) * DM_ + k0s + sc,          \
                        lb + ii * 4096 + wub);                                     \
        _Pragma("unroll")                                                          \
        for (int ii = 0; ii < 2; ++ii)                                             \
            gload_lds16(Bt + (size_t)(nseg0 + ii * 64 + sr) * DM_ + k0s + sc,      \
                        lb + ABYTES + ii * 4096 + wub);                            \
    } while (0)

    f32x4 acc[MI][NJ];
#pragma unroll
    for (int mi = 0; mi < MI; ++mi)
#pragma unroll
        for (int nj = 0; nj < NJ; ++nj) acc[mi][nj] = (f32x4){0.f, 0.f, 0.f, 0.f};

    STAGE(0, 0);

    for (int kt = 0; kt < NT; ++kt) {
        const int cur = kt & 1;
        __syncthreads();
        if (kt + 1 < NT) STAGE(cur ^ 1, kt + 1);
        const char* Ab = &lds[cur][0];
        const char* Bb = Ab + ABYTES;
        bf16x8 af[MI], bfr[NJ];
#pragma unroll
        for (int mi = 0; mi < MI; ++mi)
            af[mi] = *(const bf16x8*)(Ab + (wm * TM + mi * 16 + lc) * 64 + lg * 16);
#pragma unroll
        for (int nj = 0; nj < NJ; ++nj)
            bfr[nj] = *(const bf16x8*)(Bb + (wn * TN + nj * 16 + lc) * 64 + lg * 16);
#pragma unroll
        for (int mi = 0; mi < MI; ++mi)
#pragma unroll
            for (int nj = 0; nj < NJ; ++nj)
                acc[mi][nj] = __builtin_amdgcn_mfma_f32_16x16x32_bf16(af[mi], bfr[nj], acc[mi][nj], 0, 0, 0);
    }
#undef STAGE

    if constexpr (MODE == 0) {
        float* C = (float*)o0;
#pragma unroll
        for (int nj = 0; nj < NJ; ++nj) {
            const int n = nseg0 + wn * TN + nj * 16 + lc;
            const float bn = biasp[n];
#pragma unroll
            for (int mi = 0; mi < MI; ++mi)
#pragma unroll
                for (int r = 0; r < 4; ++r) {
                    const int m = m0 + wm * TM + mi * 16 + lg * 4 + r;
                    C[(size_t)m * DM_ + n] = acc[mi][nj][r] + bn;
                }
        }
    } else {
        if (seg < 2) {
            ushort* C = (seg == 0) ? (ushort*)o0 : (ushort*)o1;
#pragma unroll
            for (int nj = 0; nj < NJ; ++nj) {
                const int n = nseg0 + wn * TN + nj * 16 + lc;
                const float bn = biasp[n];
                const int i2 = (n & 63) & ~1;
                const bool odd = (n & 1) != 0;
#pragma unroll
                for (int mi = 0; mi < MI; ++mi)
#pragma unroll
                    for (int r = 0; r < 4; ++r) {
                        const int m = m0 + wm * TM + mi * 16 + lg * 4 + r;
                        const int s = m & (S_ - 1);
                        const float2 pz = *(const float2*)(pos + (size_t)s * DH_ + i2);
                        const float v = acc[mi][nj][r] + bn;
                        const float pv = __shfl_xor(v, 1);
                        float ov = odd ? (v * pz.y + pv * pz.x) : (v * pz.y - pv * pz.x);
                        if (seg == 0) ov *= QSCALE;
                        C[(size_t)m * (H_ * DH_) + n] = f2bf(ov);
                    }
            }
        } else {
            ushort* C = (ushort*)o2;
#pragma unroll
            for (int nj = 0; nj < NJ; ++nj) {
                const int n = nseg0 + wn * TN + nj * 16 + lc;
                const int hh = n >> 6, dd = n & 63;
                const float bn = biasp[n];
#pragma unroll
                for (int mi = 0; mi < MI; ++mi) {
                    const int mb = m0 + wm * TM + mi * 16 + lg * 4;
                    const int bb = mb >> 11, ss = mb & (S_ - 1);
                    ushort4 u;
                    u.x = f2bf(acc[mi][nj][0] + bn);
                    u.y = f2bf(acc[mi][nj][1] + bn);
                    u.z = f2bf(acc[mi][nj][2] + bn);
                    u.w = f2bf(acc[mi][nj][3] + bn);
                    *(ushort4*)(C + ((size_t)(bb * H_ + hh) * DH_ + dd) * S_ + ss) = u;
                }
            }
        }
    }
}

// ---------------------------------------------------------------------------
// bf16 MFMA flash attention — round 16: r15 kernel with THREE rotating LDS
// buffers and ONE barrier per tile (was 2). Safety: with one barrier/iter a
// wave can be at most one iteration ahead. In iter kt, STORE targets
// buf[(kt+1)%3]; a one-ahead wave stores buf[(kt+2)%3] while stragglers read
// buf[(kt+1)%3] (QK) and buf[kt%3] (PV) — all three distinct, so no
// write-under-read window exists. Register staging kept identical (the
// gload_lds swap that confounded r10's 3-buffer test is NOT applied).
// LDS 49 KB (3 blocks/CU vs 4) — acceptable: measured ~11 active waves/CU
// shows residency is not the binding constraint; barrier stalls are.
// ---------------------------------------------------------------------------
__global__ __launch_bounds__(512) void attn_mfma_kernel(
    const short* __restrict__ Qb, const short* __restrict__ Kb,
    const short* __restrict__ Vt, const int* __restrict__ vmask,
    ushort* __restrict__ O)
{
    __shared__ short Ks[3][64 * 64];
    __shared__ short Vs[3][64 * 64];
    __shared__ float bias_s[3][64];

    const int tid  = threadIdx.x;
    const int lane = tid & 63;
    const int w    = tid >> 6;        // 0..7
    const int c    = lane & 15;
    const int g    = lane >> 4;

    // T1 XCD swizzle (nwg=512, 64 per XCD): groups the 16 panel-sharing
    // blocks (same b,h) onto one XCD (validated r15: FETCH 69.8 -> 12.4).
    const int bid = (blockIdx.x % 8) * 64 + blockIdx.x / 8;
    const int qc = bid & 15;
    const int h  = (bid >> 4) & 15;
    const int b  = bid >> 8;
    const int s0 = qc * 128;

    // Q fragments (B-operand): lane holds Q[q = lane&15][k = g*8 + j]
    bf16x8 qf[2];
    {
        const size_t qbase = ((size_t)(b * S_ + s0 + w * 16 + c)) * DM_ + h * DH_ + g * 8;
        qf[0] = *(const bf16x8*)(Qb + qbase);
        qf[1] = *(const bf16x8*)(Qb + qbase + 32);
    }

    // staging: 512 threads, one 16B chunk per thread per matrix
    const int kr0 = tid >> 3, kc0 = tid & 7;
    const size_t kpan = ((size_t)b * S_) * DM_ + h * DH_;
    const size_t vpan = ((size_t)(b * H_ + h) * DH_) * S_;

    uint4 kv0, vv0;
    int mskv = 1;
    constexpr int NT = S_ / 64;

#define LOAD_TILE(KT)                                                            \
    do {                                                                         \
        kv0 = *(const uint4*)(Kb + kpan + (size_t)((KT) * 64 + kr0) * DM_ + kc0 * 8); \
        vv0 = *(const uint4*)(Vt + vpan + (size_t)kr0 * S_ + (KT) * 64 + kc0 * 8);    \
        if (tid < 64) mskv = vmask[b * S_ + (KT) * 64 + tid];                    \
    } while (0)

#define STORE_TILE(BUF)                                                          \
    do {                                                                         \
        *(uint4*)&Ks[BUF][kr0 * 64 + ((kc0 ^ (kr0 & 7)) * 8)] = kv0;             \
        *(uint4*)&Vs[BUF][kr0 * 64 + ((kc0 ^ (kr0 & 7)) * 8)] = vv0;             \
        if (tid < 64) bias_s[BUF][tid] = mskv ? 0.f : NEGV;                      \
    } while (0)

// QK^T (swapped): ACC[km] = S^T[key][q=c], init with mask bias
#define QK_TILE(ACC, BUF)                                                        \
    do {                                                                         \
        _Pragma("unroll")                                                        \
        for (int km = 0; km < 4; ++km)                                           \
            ACC[km] = *(const f32x4*)&bias_s[BUF][km * 16 + g * 4];              \
        _Pragma("unroll")                                                        \
        for (int km = 0; km < 4; ++km) {                                         \
            const int krow = km * 16 + c;                                        \
            const int swz = krow & 7;                                            \
            _Pragma("unroll")                                                    \
            for (int t2 = 0; t2 < 2; ++t2) {                                     \
                const bf16x8 kf = *(const bf16x8*)&Ks[BUF][krow * 64 +           \
                                        (((t2 * 4 + g) ^ swz) * 8)];             \
                ACC[km] = __builtin_amdgcn_mfma_f32_16x16x32_bf16(               \
                              kf, qf[t2], ACC[km], 0, 0, 0);                     \
            }                                                                    \
        }                                                                        \
    } while (0)

// softmax (defer-max) + P->bf16 + bpermute redistribution + PV from Vs[BUF]
#define SOFTMAX_PV(ACC, BUF)                                                     \
    do {                                                                         \
        float pm = -1e30f;                                                       \
        _Pragma("unroll")                                                        \
        for (int km = 0; km < 4; ++km)                                           \
            _Pragma("unroll")                                                    \
            for (int r = 0; r < 4; ++r) pm = fmaxf(pm, ACC[km][r]);              \
        pm = fmaxf(pm, __shfl_xor(pm, 16));                                      \
        pm = fmaxf(pm, __shfl_xor(pm, 32));                                      \
        if (!__all(pm <= m_run + DEFER_THR)) {                                   \
            const float m_new = fmaxf(m_run, pm);                                \
            const float sc = exp2f(m_run - m_new);                               \
            _Pragma("unroll")                                                    \
            for (int r = 0; r < 4; ++r) {                                        \
                const float scr = __shfl(sc, (lane & 48) | (g * 4 + r));         \
                _Pragma("unroll")                                                \
                for (int dg = 0; dg < 4; ++dg) acc_o[dg][r] *= scr;              \
            }                                                                    \
            l_run *= sc;                                                         \
            m_run = m_new;                                                       \
        }                                                                        \
        float p[16];                                                             \
        float tsum = 0.f;                                                        \
        _Pragma("unroll")                                                        \
        for (int km = 0; km < 4; ++km)                                           \
            _Pragma("unroll")                                                    \
            for (int r = 0; r < 4; ++r) {                                        \
                const float e = exp2f(ACC[km][r] - m_run);                       \
                p[km * 4 + r] = e;                                               \
                tsum += e;                                                       \
            }                                                                    \
        tsum += __shfl_xor(tsum, 16);                                            \
        tsum += __shfl_xor(tsum, 32);                                            \
        l_run += tsum;                                                           \
        uint32_t pk[4][2];                                                       \
        _Pragma("unroll")                                                        \
        for (int km = 0; km < 4; ++km) {                                         \
            pk[km][0] = cvt_pk_bf16(p[km * 4 + 0], p[km * 4 + 1]);               \
            pk[km][1] = cvt_pk_bf16(p[km * 4 + 2], p[km * 4 + 3]);               \
        }                                                                        \
        _Pragma("unroll")                                                        \
        for (int t2 = 0; t2 < 2; ++t2) {                                         \
            uint32_t fw[4];                                                      \
            _Pragma("unroll")                                                    \
            for (int w2 = 0; w2 < 4; ++w2) {                                     \
                const int src = (w2 < 2) ? srcA : srcB;                          \
                const uint32_t vlo = (uint32_t)__builtin_amdgcn_ds_bpermute(     \
                    src, (int)pk[2 * t2][w2 & 1]);                               \
                const uint32_t vhi = (uint32_t)__builtin_amdgcn_ds_bpermute(     \
                    src, (int)pk[2 * t2 + 1][w2 & 1]);                           \
                fw[w2] = hiSel ? vhi : vlo;                                      \
            }                                                                    \
            union { uint32_t u[4]; bf16x8 v; } pf;                               \
            pf.u[0] = fw[0]; pf.u[1] = fw[1]; pf.u[2] = fw[2]; pf.u[3] = fw[3];  \
            _Pragma("unroll")                                                    \
            for (int dg = 0; dg < 4; ++dg) {                                     \
                const int vrow = dg * 16 + c;                                    \
                const bf16x8 vf = *(const bf16x8*)&Vs[BUF][vrow * 64 +           \
                                        (((t2 * 4 + g) ^ (vrow & 7)) * 8)];      \
                acc_o[dg] = __builtin_amdgcn_mfma_f32_16x16x32_bf16(             \
                                pf.v, vf, acc_o[dg], 0, 0, 0);                   \
            }                                                                    \
        }                                                                        \
    } while (0)

    float m_run = -1e30f, l_run = 0.f;
    f32x4 acc_o[4];
#pragma unroll
    for (int dg = 0; dg < 4; ++dg) acc_o[dg] = (f32x4){0.f, 0.f, 0.f, 0.f};

    const int srcA = ((((g & 1) * 2) << 4) + c) * 4;
    const int srcB = ((((g & 1) * 2 + 1) << 4) + c) * 4;
    const bool hiSel = (lane >= 32);

    // ---- prologue: tile 0 into buf0, QK(0)
    LOAD_TILE(0);
    STORE_TILE(0);
    __syncthreads();                  // buf0 + bias ready
    LOAD_TILE(1);
    f32x4 acc_t[4];
    QK_TILE(acc_t, 0);

    // ---- main loop: ONE barrier per tile, 3-buffer rotation.
    // iter kt: STORE tile kt+1 -> buf[bnx]; barrier; prefetch tile kt+2;
    // QK(kt+1) from buf[bnx]; SOFTMAX_PV(kt) from buf[bcur].
    int bcur = 0, bnx = 1, bnn = 2;
    for (int kt = 0; kt < NT - 1; ++kt) {
        STORE_TILE(bnx);                       // regs hold tile kt+1
        __syncthreads();                       // publishes buf[bnx]
        if (kt + 2 < NT) LOAD_TILE(kt + 2);    // prefetch tile kt+2 into regs
        f32x4 acc_n[4];
        QK_TILE(acc_n, bnx);                   // MFMA pipe: scores(kt+1)
        SOFTMAX_PV(acc_t, bcur);               // VALU overlaps MFMA above
#pragma unroll
        for (int km = 0; km < 4; ++km) acc_t[km] = acc_n[km];
        const int t = bcur; bcur = bnx; bnx = bnn; bnn = t;
    }
    // ---- epilogue: finish last tile (scores computed from buf[bcur])
    SOFTMAX_PV(acc_t, bcur);

#undef LOAD_TILE
#undef STORE_TILE
#undef QK_TILE
#undef SOFTMAX_PV

    // ---- normalize and write O (bf16)
    const float linv = 1.0f / l_run;
#pragma unroll
    for (int r = 0; r < 4; ++r) {
        const float lr = __shfl(linv, (lane & 48) | (g * 4 + r));
        const int row = s0 + w * 16 + g * 4 + r;
        const size_t ob = ((size_t)(b * S_ + row)) * DM_ + h * DH_;
#pragma unroll
        for (int dg = 0; dg < 4; ++dg)
            O[ob + dg * 16 + c] = f2bf(acc_o[dg][r] * lr);
    }
}

// ---------------------------------------------------------------------------
extern "C" void kernel_launch(void* const* d_in, const int* in_sizes, int n_in,
                              void* d_out, int out_size, void* d_ws, size_t ws_size,
                              hipStream_t stream)
{
    const float* x     = (const float*)d_in[0];
    const int*   vmask = (const int*)d_in[1];
    const float* pos   = (const float*)d_in[2];
    const float* Wq    = (const float*)d_in[3];
    const float* bq    = (const float*)d_in[4];
    const float* Wk    = (const float*)d_in[5];
    const float* bk    = (const float*)d_in[6];
    const float* Wv    = (const float*)d_in[7];
    const float* bv    = (const float*)d_in[8];
    const float* Wo    = (const float*)d_in[9];
    const float* bo    = (const float*)d_in[10];
    float* out = (float*)d_out;

    const size_t MN = (size_t)(B_ * S_) * (H_ * DH_);   // 4M elems

    ushort* xb  = (ushort*)d_ws;          // 8 MB
    ushort* Wtq = xb + MN;                // 2 MB each
    ushort* Wtk = Wtq + 1024 * 1024;
    ushort* Wtv = Wtk + 1024 * 1024;
    ushort* Wto = Wtv + 1024 * 1024;
    ushort* Qb  = Wto + 1024 * 1024;      // 8 MB each
    ushort* Kb  = Qb + MN;
    ushort* Vt  = Kb + MN;
    ushort* Ob  = Vt + MN;

    // merged prep: x conversion (2048 blocks) + 4 weight transposes (1024)
    prep_kernel<<<3072, 256, 0, stream>>>(x, xb, Wq, Wk, Wv, Wo,
                                          Wtq, Wtk, Wtv, Wto);

    // fused QKV: grid = 768 blocks (3/CU), XCD-swizzled internally
    gemm_bf16<1><<<768, 256, 0, stream>>>(xb, Wtq, Wtk, Wtv, bq, bk, bv, pos,
                                          (void*)Qb, (void*)Kb, (void*)Vt);

    // attention: 512 blocks x 512 threads, XCD-swizzled internally
    attn_mfma_kernel<<<B_ * H_ * (S_ / 128), 512, 0, stream>>>(
        (const short*)Qb, (const short*)Kb, (const short*)Vt, vmask, Ob);

    // out-proj: grid = 512 blocks (2/CU), XCD-swizzled internally
    gemm_bf16<0><<<512, 256, 0, stream>>>(Ob, Wto, nullptr, nullptr, bo, nullptr, nullptr,
                                          nullptr, (void*)out, nullptr, nullptr);
}